// Round 10
// baseline (230.816 us; speedup 1.0000x reference)
//
#include <hip/hip_runtime.h>
#include <hip/hip_bf16.h>
#include <math.h>

typedef __attribute__((ext_vector_type(8))) short short8;
typedef __attribute__((ext_vector_type(4))) float f32x4;
typedef __attribute__((ext_vector_type(16))) float f32x16;
typedef unsigned short ushort_t;

#define N_PTS 8192

// packed-weight offsets (ushort units), fragment order [(mt*KS+ks)*64+lane][8]
#define WP1   0       // MT8 KS7
#define WP2A  28672   // MT4 KS4
#define WP2B  36864   // MT4 KS2
#define WLIN  40960   // MT4 KS2
#define WC3A  45056   // MT4 KS4
#define WC3B  53248   // MT4 KS2
#define WPN   57344   // MT8 KS3 (end 69632)
#define FBF   34816   // float index into ws: bias table [576]
#define FB_L1 0
#define FB_2A 128
#define FB_2B 192
#define FB_LIN 256
#define FB_3A 320
#define FB_3B 384
#define FB_PN 448

// output float offsets
#define OUT_SIM  0
#define OUT_DSIM 32768
#define OUT_SHAL 65536
#define OUT_DEEP 2162688   // 65536 + 4*64*8192

// LDS carve (ushort units), 16 points => 32 rows (0..15 real, 16..31 img)
#define ST1 232
#define ST2 168
#define ST3 104
#define S_X1  0        // 32*232 = 7424
#define S_X2  7424     // 32*168 = 5376 -> 12800
#define S_X3A 12800    // 32*104 = 3328 -> 16128
#define S_X3B 16128    // 3328 -> 19456
#define S_X4  0        // overlay X1: [16][104] -> 1664
#define S_F2  1664     // overlay X1: [16][104] -> 3328

__device__ __forceinline__ ushort_t f2bf(float x) {
    __hip_bfloat16 hv = __float2bfloat16(x);
    return *reinterpret_cast<ushort_t*>(&hv);
}
__device__ __forceinline__ float bf2f(ushort_t h) {
    return __uint_as_float(((unsigned)h) << 16);
}

// ---- single fused weight+bias pack -----------------------------------------
__global__ __launch_bounds__(256)
void prep_all(const float* __restrict__ sW, const float* __restrict__ sb,
              const float* __restrict__ sg, const float* __restrict__ sbt,
              const float* __restrict__ aW, const float* __restrict__ ab,
              const float* __restrict__ ag, const float* __restrict__ abt,
              const float* __restrict__ bW, const float* __restrict__ bb_,
              const float* __restrict__ bg, const float* __restrict__ bbt,
              const float* __restrict__ lW, const float* __restrict__ lb,
              const float* __restrict__ cW, const float* __restrict__ cb,
              const float* __restrict__ cg, const float* __restrict__ cbt,
              const float* __restrict__ dW, const float* __restrict__ db,
              const float* __restrict__ dg, const float* __restrict__ dbt,
              const float* __restrict__ pW, const float* __restrict__ pb,
              const float* __restrict__ pg, const float* __restrict__ pbt,
              ushort_t* __restrict__ wsp) {
    int g = blockIdx.x * 256 + threadIdx.x;
    if (g >= 9280) return;
    if (g >= 8704) {                       // ---- bias table (576 floats) ----
        int idx = g - 8704;
        const float *B, *G, *BT; int m, has_bn;
        if (idx < 128)      { B=sb;  G=sg; BT=sbt; m=idx;       has_bn=1; }
        else if (idx < 192) { B=ab;  G=ag; BT=abt; m=idx-128;   has_bn=1; }
        else if (idx < 256) { B=bb_; G=bg; BT=bbt; m=idx-192;   has_bn=1; }
        else if (idx < 320) { B=lb;  G=lb; BT=lb;  m=idx-256;   has_bn=0; }
        else if (idx < 384) { B=cb;  G=cg; BT=cbt; m=idx-320;   has_bn=1; }
        else if (idx < 448) { B=db;  G=dg; BT=dbt; m=idx-384;   has_bn=1; }
        else                { B=pb;  G=pg; BT=pbt; m=idx-448;   has_bn=1; }
        ((float*)wsp)[FBF + idx] = has_bn ? fmaf(G[m], B[m], BT[m]) : B[m];
        return;
    }
    const float *W, *G;
    int in_c, KS, mode, has_bn, off;
    if (g < 3584)      {           W=sW; G=sg; in_c=195; KS=7; mode=1; has_bn=1; off=WP1;  }
    else if (g < 4608) { g -= 3584; W=aW; G=ag; in_c=128; KS=4; mode=0; has_bn=1; off=WP2A; }
    else if (g < 5120) { g -= 4608; W=bW; G=bg; in_c=64;  KS=2; mode=0; has_bn=1; off=WP2B; }
    else if (g < 5632) { g -= 5120; W=lW; G=lW; in_c=64;  KS=2; mode=0; has_bn=0; off=WLIN; }
    else if (g < 6656) { g -= 5632; W=cW; G=cg; in_c=128; KS=4; mode=0; has_bn=1; off=WC3A; }
    else if (g < 7168) { g -= 6656; W=dW; G=dg; in_c=64;  KS=2; mode=0; has_bn=1; off=WC3B; }
    else               { g -= 7168; W=pW; G=pg; in_c=67;  KS=3; mode=2; has_bn=1; off=WPN;  }

    int lane = g & 63, u = g >> 6, ks = u % KS, mt = u / KS;
    int m  = mt * 16 + (lane & 15);
    int k0 = ks * 32 + ((lane >> 4) << 3);
    float scale = has_bn ? G[m] : 1.0f;
    ushort_t o[8];
    #pragma unroll
    for (int i = 0; i < 8; ++i) {
        int k = k0 + i; float v = 0.0f;
        if (mode == 1) {          // L1: k = [repre 0..191 ; pts 192..194]
            if (k < 192)      v = W[m * 195 + 3 + k] * scale;
            else if (k < 195) v = W[m * 195 + (k - 192)] * scale;
        } else if (mode == 2) {   // PN2: k = [fused 0..63 ; pts 64..66]
            if (k < 64)       v = W[m * 67 + 3 + k] * scale;
            else if (k < 67)  v = W[m * 67 + (k - 64)] * scale;
        } else {
            if (k < in_c)     v = W[m * in_c + k] * scale;
        }
        o[i] = f2bf(v);
    }
    ushort4 lo, hi;
    lo.x = o[0]; lo.y = o[1]; lo.z = o[2]; lo.w = o[3];
    hi.x = o[4]; hi.y = o[5]; hi.z = o[6]; hi.w = o[7];
    int t = (((mt * KS + ks) * 64) + lane) * 8 + off;
    *(ushort4*)(wsp + t)     = lo;
    *(ushort4*)(wsp + t + 4) = hi;
}

template<int KS, int NTS>
__device__ __forceinline__ void mfma_tiles(const short8* __restrict__ WP,
                                           const float* __restrict__ fb,
                                           int mt, int nt0,
                                           const ushort_t* __restrict__ Xin, int sin,
                                           int lane, f32x4 acc[NTS]) {
    float4 b4 = *(const float4*)(fb + mt * 16 + ((lane >> 4) << 2));
    #pragma unroll
    for (int t = 0; t < NTS; ++t) acc[t] = (f32x4){b4.x, b4.y, b4.z, b4.w};
    #pragma unroll
    for (int ks = 0; ks < KS; ++ks) {
        short8 a = WP[(mt * KS + ks) * 64 + lane];
        #pragma unroll
        for (int t = 0; t < NTS; ++t) {
            const short8 bv = *(const short8*)(Xin + ((lane & 15) + (nt0 + t) * 16) * sin
                                               + ks * 32 + ((lane >> 4) << 3));
            acc[t] = __builtin_amdgcn_mfma_f32_16x16x32_bf16(a, bv, acc[t], 0, 0, 0);
        }
    }
}

template<int NTS>
__device__ __forceinline__ void epi_relu_lds(const f32x4 acc[NTS], int mt, int nt0,
                                             int h, int p, ushort_t* Xout, int sout) {
    int ch0 = mt * 16 + h * 4;
    #pragma unroll
    for (int t = 0; t < NTS; ++t) {
        int pt = p + (nt0 + t) * 16;
        ushort4 u;
        u.x = f2bf(fmaxf(acc[t].x, 0.f)); u.y = f2bf(fmaxf(acc[t].y, 0.f));
        u.z = f2bf(fmaxf(acc[t].z, 0.f)); u.w = f2bf(fmaxf(acc[t].w, 0.f));
        *(ushort4*)(Xout + pt * sout + ch0) = u;
    }
}

__device__ __forceinline__ float fold16(const f32x16 a) {
    float t0 = fminf(fminf(a[0], a[1]), a[2]);
    float t1 = fminf(fminf(a[3], a[4]), a[5]);
    float t2 = fminf(fminf(a[6], a[7]), a[8]);
    float t3 = fminf(fminf(a[9], a[10]), a[11]);
    float t4 = fminf(fminf(a[12], a[13]), a[14]);
    float s0 = fminf(fminf(t0, t1), t2);
    float s1 = fminf(fminf(t3, t4), a[15]);
    return fminf(s0, s1);
}

// dist for one point via 32x32 MFMA; img rows at +16
__device__ __forceinline__ void dist_point(const ushort_t* __restrict__ X1base,
                                           int pt, int lane, float* __restrict__ DMIN) {
    const short8 zero8 = {0, 0, 0, 0, 0, 0, 0, 0};
    const int m32 = lane & 31;
    const int h2  = lane >> 5;
    const ushort_t* rrow = X1base + pt * ST1;
    const ushort_t* irow = X1base + (16 + pt) * ST1;
    float px = bf2f(rrow[192]), py = bf2f(rrow[193]), pz = bf2f(rrow[194]);
    short8 af[2], bfr[2];
    #pragma unroll
    for (int c = 0; c < 2; ++c) {
        int k = c * 32 + m32;
        float rx = bf2f(rrow[k]) - px;
        float ry = bf2f(rrow[64 + k]) - py;
        float rz = bf2f(rrow[128 + k]) - pz;
        float r2 = fmaf(rx, rx, fmaf(ry, ry, rz * rz));
        short8 t = zero8;
        t[0] = (short)f2bf(-2.0f * rx); t[1] = (short)f2bf(-2.0f * ry);
        t[2] = (short)f2bf(-2.0f * rz); t[3] = (short)f2bf(r2);
        t[4] = (short)0x3F80;
        af[c] = h2 ? zero8 : t;
        float fx = bf2f(irow[k]) - px;
        float fy = bf2f(irow[64 + k]) - py;
        float fz = bf2f(irow[128 + k]) - pz;
        float i2 = fmaf(fx, fx, fmaf(fy, fy, fz * fz));
        short8 s = zero8;
        s[0] = (short)f2bf(fx); s[1] = (short)f2bf(fy); s[2] = (short)f2bf(fz);
        s[3] = (short)0x3F80;   s[4] = (short)f2bf(i2);
        bfr[c] = h2 ? zero8 : s;
    }
    float dmin = 3.0e38f;
    #pragma unroll
    for (int kc = 0; kc < 2; ++kc) {
        #pragma unroll
        for (int lc = 0; lc < 2; ++lc) {
            f32x16 acc = {0.f,0.f,0.f,0.f,0.f,0.f,0.f,0.f,
                          0.f,0.f,0.f,0.f,0.f,0.f,0.f,0.f};
            acc = __builtin_amdgcn_mfma_f32_32x32x16_bf16(af[kc], bfr[lc], acc, 0, 0, 0);
            dmin = fminf(dmin, fold16(acc));
        }
    }
    #pragma unroll
    for (int off = 32; off > 0; off >>= 1)
        dmin = fminf(dmin, __shfl_xor(dmin, off, 64));
    if (lane == 0) DMIN[pt] = dmin;
}

__global__ __launch_bounds__(512, 8)
void fused_all(const float* __restrict__ img,   // [4][3][8192][64]
               const float* __restrict__ knn,   // [4][3][64][8192]
               const float* __restrict__ pts,   // [4][3][8192]
               const float* __restrict__ f2d,   // [4][64][8192]
               const float* __restrict__ fw1p, const float* __restrict__ fw2p,
               const float* __restrict__ fw3p,
               const ushort_t* __restrict__ wsp, float* __restrict__ out)
{
    __shared__ ushort_t SMEM[19456];
    __shared__ float DMIN[16];
    __shared__ float RBUF[3][4][16];

    const int tid  = threadIdx.x;
    const int wid  = __builtin_amdgcn_readfirstlane(tid >> 6);
    const int lane = tid & 63;
    const int p16  = lane & 15;
    const int h    = lane >> 4;
    const int b      = blockIdx.x >> 8;          // 1024 blocks = 4 b x 256 block-tiles
    const int n0base = (blockIdx.x & 255) << 5;  // 32 points per block (2 tiles of 16)

    const int mt64 = wid & 3;
    const int nt1  = wid >> 2;

    const float* fbias = (const float*)wsp + FBF;
    f32x4 a2[2], a1[1];

    // staging thread mappings (fixed across tiles)
    const int spt = tid & 15, sgg = tid >> 4;    // knn: 16 pts x 32 groups x 6 ch
    const int ipt = tid >> 5, iq  = tid & 31;    // img: 16 pts x 32 q (2 ch each)

    float  knv1[6];                               // tile-1 knn prefetch
    float2 imv1[3];                               // tile-1 img prefetch

    #pragma unroll 1
    for (int t = 0; t < 2; ++t) {
        const int n0 = n0base + (t << 4);
        float fpre[4] = {0.f, 0.f, 0.f, 0.f};

        // ============== phase 0: stage knn(rows 0..15) + img(16..31) =======
        for (int e = tid; e < 32 * 29; e += 512) {       // X1 zero cols 195..223
            int r = e / 29, c = 195 + e % 29;
            SMEM[S_X1 + r * ST1 + c] = 0;
        }
        if (t == 0) {
            #pragma unroll
            for (int jp = 0; jp < 3; ++jp) {             // knn tile0 + tile1 issue
                int ck = sgg * 6 + jp * 2;
                int c = ck >> 6, k = ck & 63;
                const float* base = knn + ((size_t)(b * 3 + c) * 64 + k) * N_PTS + n0base + spt;
                ushort2 u;
                u.x = f2bf(base[0]);
                u.y = f2bf(base[(size_t)N_PTS]);
                *(ushort2*)(SMEM + S_X1 + spt * ST1 + ck) = u;
                knv1[jp * 2]     = base[16];             // tile-1 prefetch (in flight)
                knv1[jp * 2 + 1] = base[(size_t)N_PTS + 16];
            }
            #pragma unroll
            for (int c = 0; c < 3; ++c) {                // img tile0 + tile1 issue
                const float* ib = img + (((size_t)(b * 3 + c)) * N_PTS + n0base + ipt) * 64 + iq * 2;
                float2 v = *(const float2*)ib;
                ushort2 u;
                u.x = f2bf(v.x); u.y = f2bf(v.y);
                *(ushort2*)(SMEM + S_X1 + (16 + ipt) * ST1 + c * 64 + iq * 2) = u;
                imv1[c] = *(const float2*)(ib + (size_t)16 * 64);   // point ipt+16
            }
        } else {
            #pragma unroll
            for (int jp = 0; jp < 3; ++jp) {             // knn tile1 from regs
                int ck = sgg * 6 + jp * 2;
                ushort2 u;
                u.x = f2bf(knv1[jp * 2]);
                u.y = f2bf(knv1[jp * 2 + 1]);
                *(ushort2*)(SMEM + S_X1 + spt * ST1 + ck) = u;
            }
            #pragma unroll
            for (int c = 0; c < 3; ++c) {                // img tile1 from regs
                ushort2 u;
                u.x = f2bf(imv1[c].x); u.y = f2bf(imv1[c].y);
                *(ushort2*)(SMEM + S_X1 + (16 + ipt) * ST1 + c * 64 + iq * 2) = u;
            }
        }
        if (tid < 96) {                                  // pts ch 192..194, all rows
            int c = tid >> 5, r = tid & 31;
            SMEM[S_X1 + r * ST1 + 192 + c] = f2bf(pts[((size_t)(b * 3 + c)) * N_PTS + n0 + (r & 15)]);
        }
        __syncthreads();   // B1

        // ============== phase 1: L1 (32 rows) ==============================
        mfma_tiles<7, 2>((const short8*)(wsp + WP1), fbias + FB_L1, wid, 0,
                         SMEM + S_X1, ST1, lane, a2);
        epi_relu_lds<2>(a2, wid, 0, h, p16, SMEM + S_X2, ST2);
        __syncthreads();   // B2

        // ============== phase 2: L2A (32 rows) + dist j=0 ==================
        mfma_tiles<4, 1>((const short8*)(wsp + WP2A), fbias + FB_2A, mt64, nt1,
                         SMEM + S_X2, ST2, lane, a1);
        epi_relu_lds<1>(a1, mt64, nt1, h, p16, SMEM + S_X3A, ST3);
        dist_point(SMEM + S_X1, wid * 2, lane, DMIN);
        __syncthreads();   // B3

        // ============== phase 3: L2B + SHAL stores + dist j=1 ==============
        mfma_tiles<2, 1>((const short8*)(wsp + WP2B), fbias + FB_2B, mt64, nt1,
                         SMEM + S_X3A, ST3, lane, a1);
        {
            int ch0 = mt64 * 16 + h * 4;
            int row = p16 + nt1 * 16;
            float v0 = fmaxf(a1[0].x, 0.f), v1 = fmaxf(a1[0].y, 0.f);
            float v2 = fmaxf(a1[0].z, 0.f), v3 = fmaxf(a1[0].w, 0.f);
            ushort4 u;
            u.x = f2bf(v0); u.y = f2bf(v1); u.z = f2bf(v2); u.w = f2bf(v3);
            *(ushort4*)(SMEM + S_X3B + row * ST3 + ch0) = u;
            if (nt1 == 0) {
                size_t base = OUT_SHAL + ((size_t)(b * 64 + ch0)) * N_PTS + n0 + p16;
                out[base]             = v0;
                out[base + N_PTS]     = v1;
                out[base + 2 * N_PTS] = v2;
                out[base + 3 * N_PTS] = v3;
            }
        }
        dist_point(SMEM + S_X1, wid * 2 + 1, lane, DMIN);
        __syncthreads();   // B4

        // ======== phase 4: LIN+cos (waves 0..3) | statics+preload (4..7) ===
        if (wid < 4) {
            f32x4 sv[2];
            mfma_tiles<2, 2>((const short8*)(wsp + WLIN), fbias + FB_LIN, wid, 0,
                             SMEM + S_X3B, ST3, lane, sv);
            float pn = sv[0].x * sv[1].x + sv[0].y * sv[1].y + sv[0].z * sv[1].z + sv[0].w * sv[1].w;
            float pr = sv[0].x * sv[0].x + sv[0].y * sv[0].y + sv[0].z * sv[0].z + sv[0].w * sv[0].w;
            float pi = sv[1].x * sv[1].x + sv[1].y * sv[1].y + sv[1].z * sv[1].z + sv[1].w * sv[1].w;
            pn += __shfl_xor(pn, 16, 64); pn += __shfl_xor(pn, 32, 64);
            pr += __shfl_xor(pr, 16, 64); pr += __shfl_xor(pr, 32, 64);
            pi += __shfl_xor(pi, 16, 64); pi += __shfl_xor(pi, 32, 64);
            if (lane < 16) {
                RBUF[0][wid][p16] = pn;
                RBUF[1][wid][p16] = pr;
                RBUF[2][wid][p16] = pi;
            }
        } else {
            int t256 = tid - 256;                        // 0..255
            int pt = t256 & 15, cg = t256 >> 4;
            #pragma unroll
            for (int r = 0; r < 4; ++r)
                fpre[r] = f2d[((size_t)(b * 64 + cg * 4 + r)) * N_PTS + n0 + pt];
            if (t256 < 48) {                             // X4 pts ch64..66
                int c = t256 >> 4, r = t256 & 15;
                SMEM[S_X4 + r * ST3 + 64 + c] = f2bf(pts[((size_t)(b * 3 + c)) * N_PTS + n0 + r]);
            }
            for (int e = t256; e < 16 * 29; e += 256) {  // X4 zero cols 67..95
                int r = e / 29, c = 67 + e % 29;
                SMEM[S_X4 + r * ST3 + c] = 0;
            }
        }
        __syncthreads();   // B5

        // ======== phase 5: sim (redundant per-thread) + F2 fill ============
        if (wid >= 4) {
            int t256 = tid - 256;
            int pt = t256 & 15, cg = t256 >> 4;
            float num = 0.f, rr = 0.f, ii = 0.f;
            #pragma unroll
            for (int m = 0; m < 4; ++m) {
                num += RBUF[0][m][pt];
                rr  += RBUF[1][m][pt];
                ii  += RBUF[2][m][pt];
            }
            float den = fmaxf(sqrtf(rr) * sqrtf(ii), 1e-8f);
            float geo = expf(-(1.0f / fw1p[0]) * DMIN[pt]) + fw2p[0];
            float sim = (num / den) * geo;
            ushort4 u;
            u.x = f2bf(sim * fpre[0]); u.y = f2bf(sim * fpre[1]);
            u.z = f2bf(sim * fpre[2]); u.w = f2bf(sim * fpre[3]);
            *(ushort4*)(SMEM + S_F2 + pt * ST3 + cg * 4) = u;
            if (cg == 0) {
                out[OUT_SIM  + (size_t)b * N_PTS + n0 + pt] = sim;
                out[OUT_DSIM + (size_t)b * N_PTS + n0 + pt] = fw3p[0];
            }
        }
        __syncthreads();   // B6

        // ======== phase 6: C3A [X3B real ; F2] -> X3A rows 0..15 ===========
        if (wid < 4) {
            const short8* W = (const short8*)(wsp + WC3A);
            float4 b4 = *(const float4*)(fbias + FB_3A + wid * 16 + (h << 2));
            f32x4 a = (f32x4){b4.x, b4.y, b4.z, b4.w};
            int row = p16 * ST3 + (h << 3);
            #pragma unroll
            for (int ks = 0; ks < 4; ++ks) {
                short8 aw = W[(wid * 4 + ks) * 64 + lane];
                const ushort_t* src = (ks < 2)
                    ? (SMEM + S_X3B + row + ks * 32)
                    : (SMEM + S_F2  + row + (ks - 2) * 32);
                a = __builtin_amdgcn_mfma_f32_16x16x32_bf16(aw, *(const short8*)src, a, 0, 0, 0);
            }
            a1[0] = a;
            epi_relu_lds<1>(a1, wid, 0, h, p16, SMEM + S_X3A, ST3);
        }
        __syncthreads();   // B7

        // ======== phase 7: C3B -> X4 ch0..63 rows 0..15 ====================
        if (wid < 4) {
            mfma_tiles<2, 1>((const short8*)(wsp + WC3B), fbias + FB_3B, wid, 0,
                             SMEM + S_X3A, ST3, lane, a1);
            epi_relu_lds<1>(a1, wid, 0, h, p16, SMEM + S_X4, ST3);
        }
        __syncthreads();   // B8

        // ======== phase 8: PN2 -> deeprealfeat =============================
        mfma_tiles<3, 1>((const short8*)(wsp + WPN), fbias + FB_PN, wid, 0,
                         SMEM + S_X4, ST3, lane, a1);
        {
            int ch0 = wid * 16 + h * 4;
            size_t base = OUT_DEEP + ((size_t)(b * 128 + ch0)) * N_PTS + n0 + p16;
            out[base]             = fmaxf(a1[0].x, 0.f);
            out[base + N_PTS]     = fmaxf(a1[0].y, 0.f);
            out[base + 2 * N_PTS] = fmaxf(a1[0].z, 0.f);
            out[base + 3 * N_PTS] = fmaxf(a1[0].w, 0.f);
        }
        if (t == 0) __syncthreads();   // B9: protect X1/X4/F2 before tile-1 staging
    }
}

extern "C" void kernel_launch(void* const* d_in, const int* in_sizes, int n_in,
                              void* d_out, int out_size, void* d_ws, size_t ws_size,
                              hipStream_t stream) {
    const float* img    = (const float*)d_in[0];
    const float* knn    = (const float*)d_in[1];
    const float* pts    = (const float*)d_in[2];
    const float* f2d    = (const float*)d_in[3];
    const float* sift_W = (const float*)d_in[4];
    const float* sift_b = (const float*)d_in[5];
    const float* sift_g = (const float*)d_in[6];
    const float* sift_bt= (const float*)d_in[7];
    const float* c2_W1  = (const float*)d_in[8];
    const float* c2_b1  = (const float*)d_in[9];
    const float* c2_g1  = (const float*)d_in[10];
    const float* c2_bt1 = (const float*)d_in[11];
    const float* c2_W2  = (const float*)d_in[12];
    const float* c2_b2  = (const float*)d_in[13];
    const float* c2_g2  = (const float*)d_in[14];
    const float* c2_bt2 = (const float*)d_in[15];
    const float* lin1_W = (const float*)d_in[16];
    const float* lin1_b = (const float*)d_in[17];
    const float* c3_W1  = (const float*)d_in[18];
    const float* c3_b1  = (const float*)d_in[19];
    const float* c3_g1  = (const float*)d_in[20];
    const float* c3_bt1 = (const float*)d_in[21];
    const float* c3_W2  = (const float*)d_in[22];
    const float* c3_b2  = (const float*)d_in[23];
    const float* c3_g2  = (const float*)d_in[24];
    const float* c3_bt2 = (const float*)d_in[25];
    const float* pn2_W  = (const float*)d_in[26];
    const float* pn2_b  = (const float*)d_in[27];
    const float* pn2_g  = (const float*)d_in[28];
    const float* pn2_bt = (const float*)d_in[29];
    const float* fw1    = (const float*)d_in[30];
    const float* fw2    = (const float*)d_in[31];
    const float* fw3    = (const float*)d_in[32];

    ushort_t* wsp = (ushort_t*)d_ws;
    float* out = (float*)d_out;

    prep_all<<<37, 256, 0, stream>>>(
        sift_W, sift_b, sift_g, sift_bt,
        c2_W1, c2_b1, c2_g1, c2_bt1,
        c2_W2, c2_b2, c2_g2, c2_bt2,
        lin1_W, lin1_b,
        c3_W1, c3_b1, c3_g1, c3_bt1,
        c3_W2, c3_b2, c3_g2, c3_bt2,
        pn2_W, pn2_b, pn2_g, pn2_bt,
        wsp);

    fused_all<<<1024, 512, 0, stream>>>(img, knn, pts, f2d, fw1, fw2, fw3, wsp, out);
}

// Round 11
// 42.318 us; speedup vs baseline: 5.4543x; 5.4543x over previous
//
#include <hip/hip_runtime.h>
#include <hip/hip_bf16.h>
#include <math.h>

// ===== round-8 configuration (best: 42.07 us) =====
// Protected decisions (each regressed when changed):
//  - 16-point n-tiles (8-pt tiles: +73% HBM over-fetch, r9)
//  - 512-thread blocks, 1 tile per block (2-tile reg pipeline: scratch spill, r10)
//  - 16B-aligned LDS strides 232/168/104 (odd strides: misaligned b128, r7)

typedef __attribute__((ext_vector_type(8))) short short8;
typedef __attribute__((ext_vector_type(4))) float f32x4;
typedef __attribute__((ext_vector_type(16))) float f32x16;
typedef unsigned short ushort_t;

#define N_PTS 8192

// packed-weight offsets (ushort units), fragment order [(mt*KS+ks)*64+lane][8]
#define WP1   0       // MT8 KS7
#define WP2A  28672   // MT4 KS4
#define WP2B  36864   // MT4 KS2
#define WLIN  40960   // MT4 KS2
#define WC3A  45056   // MT4 KS4
#define WC3B  53248   // MT4 KS2
#define WPN   57344   // MT8 KS3 (end 69632)
#define FBF   34816   // float index into ws: bias table [576]
#define FB_L1 0
#define FB_2A 128
#define FB_2B 192
#define FB_LIN 256
#define FB_3A 320
#define FB_3B 384
#define FB_PN 448

// output float offsets
#define OUT_SIM  0
#define OUT_DSIM 32768
#define OUT_SHAL 65536
#define OUT_DEEP 2162688   // 65536 + 4*64*8192

// LDS carve (ushort units), 16 points => 32 rows (0..15 real, 16..31 img)
#define ST1 232
#define ST2 168
#define ST3 104
#define S_X1  0        // 32*232 = 7424
#define S_X2  7424     // 32*168 = 5376 -> 12800
#define S_X3A 12800    // 32*104 = 3328 -> 16128
#define S_X3B 16128    // 3328 -> 19456
#define S_X4  0        // overlay X1: [16][104] -> 1664
#define S_F2  1664     // overlay X1: [16][104] -> 3328

__device__ __forceinline__ ushort_t f2bf(float x) {
    __hip_bfloat16 hv = __float2bfloat16(x);
    return *reinterpret_cast<ushort_t*>(&hv);
}
__device__ __forceinline__ float bf2f(ushort_t h) {
    return __uint_as_float(((unsigned)h) << 16);
}

// ---- single fused weight+bias pack -----------------------------------------
__global__ __launch_bounds__(256)
void prep_all(const float* __restrict__ sW, const float* __restrict__ sb,
              const float* __restrict__ sg, const float* __restrict__ sbt,
              const float* __restrict__ aW, const float* __restrict__ ab,
              const float* __restrict__ ag, const float* __restrict__ abt,
              const float* __restrict__ bW, const float* __restrict__ bb_,
              const float* __restrict__ bg, const float* __restrict__ bbt,
              const float* __restrict__ lW, const float* __restrict__ lb,
              const float* __restrict__ cW, const float* __restrict__ cb,
              const float* __restrict__ cg, const float* __restrict__ cbt,
              const float* __restrict__ dW, const float* __restrict__ db,
              const float* __restrict__ dg, const float* __restrict__ dbt,
              const float* __restrict__ pW, const float* __restrict__ pb,
              const float* __restrict__ pg, const float* __restrict__ pbt,
              ushort_t* __restrict__ wsp) {
    int g = blockIdx.x * 256 + threadIdx.x;
    if (g >= 9280) return;
    if (g >= 8704) {                       // ---- bias table (576 floats) ----
        int idx = g - 8704;
        const float *B, *G, *BT; int m, has_bn;
        if (idx < 128)      { B=sb;  G=sg; BT=sbt; m=idx;       has_bn=1; }
        else if (idx < 192) { B=ab;  G=ag; BT=abt; m=idx-128;   has_bn=1; }
        else if (idx < 256) { B=bb_; G=bg; BT=bbt; m=idx-192;   has_bn=1; }
        else if (idx < 320) { B=lb;  G=lb; BT=lb;  m=idx-256;   has_bn=0; }
        else if (idx < 384) { B=cb;  G=cg; BT=cbt; m=idx-320;   has_bn=1; }
        else if (idx < 448) { B=db;  G=dg; BT=dbt; m=idx-384;   has_bn=1; }
        else                { B=pb;  G=pg; BT=pbt; m=idx-448;   has_bn=1; }
        ((float*)wsp)[FBF + idx] = has_bn ? fmaf(G[m], B[m], BT[m]) : B[m];
        return;
    }
    const float *W, *G;
    int in_c, KS, mode, has_bn, off;
    if (g < 3584)      {           W=sW; G=sg; in_c=195; KS=7; mode=1; has_bn=1; off=WP1;  }
    else if (g < 4608) { g -= 3584; W=aW; G=ag; in_c=128; KS=4; mode=0; has_bn=1; off=WP2A; }
    else if (g < 5120) { g -= 4608; W=bW; G=bg; in_c=64;  KS=2; mode=0; has_bn=1; off=WP2B; }
    else if (g < 5632) { g -= 5120; W=lW; G=lW; in_c=64;  KS=2; mode=0; has_bn=0; off=WLIN; }
    else if (g < 6656) { g -= 5632; W=cW; G=cg; in_c=128; KS=4; mode=0; has_bn=1; off=WC3A; }
    else if (g < 7168) { g -= 6656; W=dW; G=dg; in_c=64;  KS=2; mode=0; has_bn=1; off=WC3B; }
    else               { g -= 7168; W=pW; G=pg; in_c=67;  KS=3; mode=2; has_bn=1; off=WPN;  }

    int lane = g & 63, u = g >> 6, ks = u % KS, mt = u / KS;
    int m  = mt * 16 + (lane & 15);
    int k0 = ks * 32 + ((lane >> 4) << 3);
    float scale = has_bn ? G[m] : 1.0f;
    ushort_t o[8];
    #pragma unroll
    for (int i = 0; i < 8; ++i) {
        int k = k0 + i; float v = 0.0f;
        if (mode == 1) {          // L1: k = [repre 0..191 ; pts 192..194]
            if (k < 192)      v = W[m * 195 + 3 + k] * scale;
            else if (k < 195) v = W[m * 195 + (k - 192)] * scale;
        } else if (mode == 2) {   // PN2: k = [fused 0..63 ; pts 64..66]
            if (k < 64)       v = W[m * 67 + 3 + k] * scale;
            else if (k < 67)  v = W[m * 67 + (k - 64)] * scale;
        } else {
            if (k < in_c)     v = W[m * in_c + k] * scale;
        }
        o[i] = f2bf(v);
    }
    ushort4 lo, hi;
    lo.x = o[0]; lo.y = o[1]; lo.z = o[2]; lo.w = o[3];
    hi.x = o[4]; hi.y = o[5]; hi.z = o[6]; hi.w = o[7];
    int t = (((mt * KS + ks) * 64) + lane) * 8 + off;
    *(ushort4*)(wsp + t)     = lo;
    *(ushort4*)(wsp + t + 4) = hi;
}

template<int KS, int NTS>
__device__ __forceinline__ void mfma_tiles(const short8* __restrict__ WP,
                                           const float* __restrict__ fb,
                                           int mt, int nt0,
                                           const ushort_t* __restrict__ Xin, int sin,
                                           int lane, f32x4 acc[NTS]) {
    float4 b4 = *(const float4*)(fb + mt * 16 + ((lane >> 4) << 2));
    #pragma unroll
    for (int t = 0; t < NTS; ++t) acc[t] = (f32x4){b4.x, b4.y, b4.z, b4.w};
    #pragma unroll
    for (int ks = 0; ks < KS; ++ks) {
        short8 a = WP[(mt * KS + ks) * 64 + lane];
        #pragma unroll
        for (int t = 0; t < NTS; ++t) {
            const short8 bv = *(const short8*)(Xin + ((lane & 15) + (nt0 + t) * 16) * sin
                                               + ks * 32 + ((lane >> 4) << 3));
            acc[t] = __builtin_amdgcn_mfma_f32_16x16x32_bf16(a, bv, acc[t], 0, 0, 0);
        }
    }
}

template<int NTS>
__device__ __forceinline__ void epi_relu_lds(const f32x4 acc[NTS], int mt, int nt0,
                                             int h, int p, ushort_t* Xout, int sout) {
    int ch0 = mt * 16 + h * 4;
    #pragma unroll
    for (int t = 0; t < NTS; ++t) {
        int pt = p + (nt0 + t) * 16;
        ushort4 u;
        u.x = f2bf(fmaxf(acc[t].x, 0.f)); u.y = f2bf(fmaxf(acc[t].y, 0.f));
        u.z = f2bf(fmaxf(acc[t].z, 0.f)); u.w = f2bf(fmaxf(acc[t].w, 0.f));
        *(ushort4*)(Xout + pt * sout + ch0) = u;
    }
}

__device__ __forceinline__ float fold16(const f32x16 a) {
    float t0 = fminf(fminf(a[0], a[1]), a[2]);
    float t1 = fminf(fminf(a[3], a[4]), a[5]);
    float t2 = fminf(fminf(a[6], a[7]), a[8]);
    float t3 = fminf(fminf(a[9], a[10]), a[11]);
    float t4 = fminf(fminf(a[12], a[13]), a[14]);
    float s0 = fminf(fminf(t0, t1), t2);
    float s1 = fminf(fminf(t3, t4), a[15]);
    return fminf(s0, s1);
}

// dist for one point via 32x32 MFMA; img rows at +16
__device__ __forceinline__ void dist_point(const ushort_t* __restrict__ X1base,
                                           int pt, int lane, float* __restrict__ DMIN) {
    const short8 zero8 = {0, 0, 0, 0, 0, 0, 0, 0};
    const int m32 = lane & 31;
    const int h2  = lane >> 5;
    const ushort_t* rrow = X1base + pt * ST1;
    const ushort_t* irow = X1base + (16 + pt) * ST1;
    float px = bf2f(rrow[192]), py = bf2f(rrow[193]), pz = bf2f(rrow[194]);
    short8 af[2], bfr[2];
    #pragma unroll
    for (int c = 0; c < 2; ++c) {
        int k = c * 32 + m32;
        float rx = bf2f(rrow[k]) - px;
        float ry = bf2f(rrow[64 + k]) - py;
        float rz = bf2f(rrow[128 + k]) - pz;
        float r2 = fmaf(rx, rx, fmaf(ry, ry, rz * rz));
        short8 t = zero8;
        t[0] = (short)f2bf(-2.0f * rx); t[1] = (short)f2bf(-2.0f * ry);
        t[2] = (short)f2bf(-2.0f * rz); t[3] = (short)f2bf(r2);
        t[4] = (short)0x3F80;
        af[c] = h2 ? zero8 : t;
        float fx = bf2f(irow[k]) - px;
        float fy = bf2f(irow[64 + k]) - py;
        float fz = bf2f(irow[128 + k]) - pz;
        float i2 = fmaf(fx, fx, fmaf(fy, fy, fz * fz));
        short8 s = zero8;
        s[0] = (short)f2bf(fx); s[1] = (short)f2bf(fy); s[2] = (short)f2bf(fz);
        s[3] = (short)0x3F80;   s[4] = (short)f2bf(i2);
        bfr[c] = h2 ? zero8 : s;
    }
    float dmin = 3.0e38f;
    #pragma unroll
    for (int kc = 0; kc < 2; ++kc) {
        #pragma unroll
        for (int lc = 0; lc < 2; ++lc) {
            f32x16 acc = {0.f,0.f,0.f,0.f,0.f,0.f,0.f,0.f,
                          0.f,0.f,0.f,0.f,0.f,0.f,0.f,0.f};
            acc = __builtin_amdgcn_mfma_f32_32x32x16_bf16(af[kc], bfr[lc], acc, 0, 0, 0);
            dmin = fminf(dmin, fold16(acc));
        }
    }
    #pragma unroll
    for (int off = 32; off > 0; off >>= 1)
        dmin = fminf(dmin, __shfl_xor(dmin, off, 64));
    if (lane == 0) DMIN[pt] = dmin;
}

__global__ __launch_bounds__(512, 8)
void fused_all(const float* __restrict__ img,   // [4][3][8192][64]
               const float* __restrict__ knn,   // [4][3][64][8192]
               const float* __restrict__ pts,   // [4][3][8192]
               const float* __restrict__ f2d,   // [4][64][8192]
               const float* __restrict__ fw1p, const float* __restrict__ fw2p,
               const float* __restrict__ fw3p,
               const ushort_t* __restrict__ wsp, float* __restrict__ out)
{
    __shared__ ushort_t SMEM[19456];
    __shared__ float DMIN[16];
    __shared__ float RBUF[3][4][16];

    const int tid  = threadIdx.x;
    const int wid  = __builtin_amdgcn_readfirstlane(tid >> 6);
    const int lane = tid & 63;
    const int p16  = lane & 15;
    const int h    = lane >> 4;
    const int b    = blockIdx.x >> 9;
    const int n0   = (blockIdx.x & 511) << 4;

    const int mt64 = wid & 3;
    const int nt1  = wid >> 2;

    const float* fbias = (const float*)wsp + FBF;
    f32x4 a2[2], a1[1];
    float fpre[4] = {0.f, 0.f, 0.f, 0.f};

    // ================= phase 0: stage knn(rows 0..15) + img(16..31) ========
    for (int e = tid; e < 32 * 29; e += 512) {           // X1 zero cols 195..223
        int r = e / 29, c = 195 + e % 29;
        SMEM[S_X1 + r * ST1 + c] = 0;
    }
    {   // knn -> rows 0..15, ch 0..191
        int pt = tid & 15, g = tid >> 4;                 // g 0..31
        #pragma unroll
        for (int jp = 0; jp < 3; ++jp) {
            int ck = g * 6 + jp * 2;
            int c = ck >> 6, k = ck & 63;
            const float* base = knn + ((size_t)(b * 3 + c) * 64 + k) * N_PTS + n0 + pt;
            ushort2 u;
            u.x = f2bf(base[0]);
            u.y = f2bf(base[(size_t)N_PTS]);
            *(ushort2*)(SMEM + S_X1 + pt * ST1 + ck) = u;
        }
    }
    {   // img -> rows 16..31, ch 0..191
        int pt = tid >> 5, q = tid & 31;
        #pragma unroll
        for (int c = 0; c < 3; ++c) {
            float2 v = *(const float2*)(img + (((size_t)(b * 3 + c)) * N_PTS + n0 + pt) * 64 + q * 2);
            ushort2 u;
            u.x = f2bf(v.x); u.y = f2bf(v.y);
            *(ushort2*)(SMEM + S_X1 + (16 + pt) * ST1 + c * 64 + q * 2) = u;
        }
    }
    if (tid < 96) {                                      // pts ch 192..194, all rows
        int c = tid >> 5, r = tid & 31;
        SMEM[S_X1 + r * ST1 + 192 + c] = f2bf(pts[((size_t)(b * 3 + c)) * N_PTS + n0 + (r & 15)]);
    }
    __syncthreads();   // B1

    // ================= phase 1: L1 (32 rows) ===============================
    mfma_tiles<7, 2>((const short8*)(wsp + WP1), fbias + FB_L1, wid, 0,
                     SMEM + S_X1, ST1, lane, a2);
    epi_relu_lds<2>(a2, wid, 0, h, p16, SMEM + S_X2, ST2);
    __syncthreads();   // B2

    // ================= phase 2: L2A (32 rows) + dist j=0 ===================
    mfma_tiles<4, 1>((const short8*)(wsp + WP2A), fbias + FB_2A, mt64, nt1,
                     SMEM + S_X2, ST2, lane, a1);
    epi_relu_lds<1>(a1, mt64, nt1, h, p16, SMEM + S_X3A, ST3);
    dist_point(SMEM + S_X1, wid * 2, lane, DMIN);
    __syncthreads();   // B3

    // ================= phase 3: L2B + SHAL stores + dist j=1 ===============
    mfma_tiles<2, 1>((const short8*)(wsp + WP2B), fbias + FB_2B, mt64, nt1,
                     SMEM + S_X3A, ST3, lane, a1);
    {
        int ch0 = mt64 * 16 + h * 4;
        int row = p16 + nt1 * 16;
        float v0 = fmaxf(a1[0].x, 0.f), v1 = fmaxf(a1[0].y, 0.f);
        float v2 = fmaxf(a1[0].z, 0.f), v3 = fmaxf(a1[0].w, 0.f);
        ushort4 u;
        u.x = f2bf(v0); u.y = f2bf(v1); u.z = f2bf(v2); u.w = f2bf(v3);
        *(ushort4*)(SMEM + S_X3B + row * ST3 + ch0) = u;
        if (nt1 == 0) {
            size_t base = OUT_SHAL + ((size_t)(b * 64 + ch0)) * N_PTS + n0 + p16;
            out[base]             = v0;
            out[base + N_PTS]     = v1;
            out[base + 2 * N_PTS] = v2;
            out[base + 3 * N_PTS] = v3;
        }
    }
    dist_point(SMEM + S_X1, wid * 2 + 1, lane, DMIN);
    __syncthreads();   // B4

    // ============ phase 4: LIN+cos (waves 0..3) | statics+preload (4..7) ===
    if (wid < 4) {
        f32x4 sv[2];
        mfma_tiles<2, 2>((const short8*)(wsp + WLIN), fbias + FB_LIN, wid, 0,
                         SMEM + S_X3B, ST3, lane, sv);
        float pn = sv[0].x * sv[1].x + sv[0].y * sv[1].y + sv[0].z * sv[1].z + sv[0].w * sv[1].w;
        float pr = sv[0].x * sv[0].x + sv[0].y * sv[0].y + sv[0].z * sv[0].z + sv[0].w * sv[0].w;
        float pi = sv[1].x * sv[1].x + sv[1].y * sv[1].y + sv[1].z * sv[1].z + sv[1].w * sv[1].w;
        pn += __shfl_xor(pn, 16, 64); pn += __shfl_xor(pn, 32, 64);
        pr += __shfl_xor(pr, 16, 64); pr += __shfl_xor(pr, 32, 64);
        pi += __shfl_xor(pi, 16, 64); pi += __shfl_xor(pi, 32, 64);
        if (lane < 16) {
            RBUF[0][wid][p16] = pn;
            RBUF[1][wid][p16] = pr;
            RBUF[2][wid][p16] = pi;
        }
    } else {
        int t256 = tid - 256;                            // 0..255
        int pt = t256 & 15, cg = t256 >> 4;
        #pragma unroll
        for (int r = 0; r < 4; ++r)
            fpre[r] = f2d[((size_t)(b * 64 + cg * 4 + r)) * N_PTS + n0 + pt];
        if (t256 < 48) {                                 // X4 pts ch64..66
            int c = t256 >> 4, r = t256 & 15;
            SMEM[S_X4 + r * ST3 + 64 + c] = f2bf(pts[((size_t)(b * 3 + c)) * N_PTS + n0 + r]);
        }
        for (int e = t256; e < 16 * 29; e += 256) {      // X4 zero cols 67..95
            int r = e / 29, c = 67 + e % 29;
            SMEM[S_X4 + r * ST3 + c] = 0;
        }
    }
    __syncthreads();   // B5

    // ============ phase 5: sim (redundant per-thread) + F2 fill ============
    if (wid >= 4) {
        int t256 = tid - 256;
        int pt = t256 & 15, cg = t256 >> 4;
        float num = 0.f, rr = 0.f, ii = 0.f;
        #pragma unroll
        for (int m = 0; m < 4; ++m) {
            num += RBUF[0][m][pt];
            rr  += RBUF[1][m][pt];
            ii  += RBUF[2][m][pt];
        }
        float den = fmaxf(sqrtf(rr) * sqrtf(ii), 1e-8f);
        float geo = expf(-(1.0f / fw1p[0]) * DMIN[pt]) + fw2p[0];
        float sim = (num / den) * geo;
        ushort4 u;
        u.x = f2bf(sim * fpre[0]); u.y = f2bf(sim * fpre[1]);
        u.z = f2bf(sim * fpre[2]); u.w = f2bf(sim * fpre[3]);
        *(ushort4*)(SMEM + S_F2 + pt * ST3 + cg * 4) = u;
        if (cg == 0) {
            out[OUT_SIM  + (size_t)b * N_PTS + n0 + pt] = sim;
            out[OUT_DSIM + (size_t)b * N_PTS + n0 + pt] = fw3p[0];
        }
    }
    __syncthreads();   // B6

    // ============ phase 6: C3A [X3B real ; F2] -> X3A rows 0..15 ===========
    if (wid < 4) {
        const short8* W = (const short8*)(wsp + WC3A);
        float4 b4 = *(const float4*)(fbias + FB_3A + wid * 16 + (h << 2));
        f32x4 a = (f32x4){b4.x, b4.y, b4.z, b4.w};
        int row = p16 * ST3 + (h << 3);
        #pragma unroll
        for (int ks = 0; ks < 4; ++ks) {
            short8 aw = W[(wid * 4 + ks) * 64 + lane];
            const ushort_t* src = (ks < 2)
                ? (SMEM + S_X3B + row + ks * 32)
                : (SMEM + S_F2  + row + (ks - 2) * 32);
            a = __builtin_amdgcn_mfma_f32_16x16x32_bf16(aw, *(const short8*)src, a, 0, 0, 0);
        }
        a1[0] = a;
        epi_relu_lds<1>(a1, wid, 0, h, p16, SMEM + S_X3A, ST3);
    }
    __syncthreads();   // B7

    // ============ phase 7: C3B -> X4 ch0..63 rows 0..15 ====================
    if (wid < 4) {
        mfma_tiles<2, 1>((const short8*)(wsp + WC3B), fbias + FB_3B, wid, 0,
                         SMEM + S_X3A, ST3, lane, a1);
        epi_relu_lds<1>(a1, wid, 0, h, p16, SMEM + S_X4, ST3);
    }
    __syncthreads();   // B8

    // ============ phase 8: PN2 -> deeprealfeat =============================
    mfma_tiles<3, 1>((const short8*)(wsp + WPN), fbias + FB_PN, wid, 0,
                     SMEM + S_X4, ST3, lane, a1);
    {
        int ch0 = wid * 16 + h * 4;
        size_t base = OUT_DEEP + ((size_t)(b * 128 + ch0)) * N_PTS + n0 + p16;
        out[base]             = fmaxf(a1[0].x, 0.f);
        out[base + N_PTS]     = fmaxf(a1[0].y, 0.f);
        out[base + 2 * N_PTS] = fmaxf(a1[0].z, 0.f);
        out[base + 3 * N_PTS] = fmaxf(a1[0].w, 0.f);
    }
}

extern "C" void kernel_launch(void* const* d_in, const int* in_sizes, int n_in,
                              void* d_out, int out_size, void* d_ws, size_t ws_size,
                              hipStream_t stream) {
    const float* img    = (const float*)d_in[0];
    const float* knn    = (const float*)d_in[1];
    const float* pts    = (const float*)d_in[2];
    const float* f2d    = (const float*)d_in[3];
    const float* sift_W = (const float*)d_in[4];
    const float* sift_b = (const float*)d_in[5];
    const float* sift_g = (const float*)d_in[6];
    const float* sift_bt= (const float*)d_in[7];
    const float* c2_W1  = (const float*)d_in[8];
    const float* c2_b1  = (const float*)d_in[9];
    const float* c2_g1  = (const float*)d_in[10];
    const float* c2_bt1 = (const float*)d_in[11];
    const float* c2_W2  = (const float*)d_in[12];
    const float* c2_b2  = (const float*)d_in[13];
    const float* c2_g2  = (const float*)d_in[14];
    const float* c2_bt2 = (const float*)d_in[15];
    const float* lin1_W = (const float*)d_in[16];
    const float* lin1_b = (const float*)d_in[17];
    const float* c3_W1  = (const float*)d_in[18];
    const float* c3_b1  = (const float*)d_in[19];
    const float* c3_g1  = (const float*)d_in[20];
    const float* c3_bt1 = (const float*)d_in[21];
    const float* c3_W2  = (const float*)d_in[22];
    const float* c3_b2  = (const float*)d_in[23];
    const float* c3_g2  = (const float*)d_in[24];
    const float* c3_bt2 = (const float*)d_in[25];
    const float* pn2_W  = (const float*)d_in[26];
    const float* pn2_b  = (const float*)d_in[27];
    const float* pn2_g  = (const float*)d_in[28];
    const float* pn2_bt = (const float*)d_in[29];
    const float* fw1    = (const float*)d_in[30];
    const float* fw2    = (const float*)d_in[31];
    const float* fw3    = (const float*)d_in[32];

    ushort_t* wsp = (ushort_t*)d_ws;
    float* out = (float*)d_out;

    prep_all<<<37, 256, 0, stream>>>(
        sift_W, sift_b, sift_g, sift_bt,
        c2_W1, c2_b1, c2_g1, c2_bt1,
        c2_W2, c2_b2, c2_g2, c2_bt2,
        lin1_W, lin1_b,
        c3_W1, c3_b1, c3_g1, c3_bt1,
        c3_W2, c3_b2, c3_g2, c3_bt2,
        pn2_W, pn2_b, pn2_g, pn2_bt,
        wsp);

    fused_all<<<2048, 512, 0, stream>>>(img, knn, pts, f2d, fw1, fw2, fw3, wsp, out);
}

// Round 12
// 40.764 us; speedup vs baseline: 5.6623x; 1.0381x over previous
//
#include <hip/hip_runtime.h>
#include <hip/hip_bf16.h>
#include <math.h>

// ===== round-8 structure + dist-table optimization =====
// Protected decisions (each regressed when changed):
//  - 16-point n-tiles (8-pt tiles: +73% HBM over-fetch, r9)
//  - 512-thread blocks, 1 tile per block (2-tile reg pipeline: scratch spill, r10)
//  - 16B-aligned LDS strides 232/168/104 (odd strides: misaligned b128, r7)

typedef __attribute__((ext_vector_type(8))) short short8;
typedef __attribute__((ext_vector_type(4))) float f32x4;
typedef __attribute__((ext_vector_type(16))) float f32x16;
typedef unsigned short ushort_t;

#define N_PTS 8192

// packed-weight offsets (ushort units), fragment order [(mt*KS+ks)*64+lane][8]
#define WP1   0       // MT8 KS7
#define WP2A  28672   // MT4 KS4
#define WP2B  36864   // MT4 KS2
#define WLIN  40960   // MT4 KS2
#define WC3A  45056   // MT4 KS4
#define WC3B  53248   // MT4 KS2
#define WPN   57344   // MT8 KS3 (end 69632)
#define FBF   34816   // float index into ws: bias table [576]
#define FB_L1 0
#define FB_2A 128
#define FB_2B 192
#define FB_LIN 256
#define FB_3A 320
#define FB_3B 384
#define FB_PN 448

// output float offsets
#define OUT_SIM  0
#define OUT_DSIM 32768
#define OUT_SHAL 65536
#define OUT_DEEP 2162688   // 65536 + 4*64*8192

// LDS carve (ushort units), 16 points => 32 rows (0..15 real, 16..31 img)
#define ST1 232
#define ST2 168
#define ST3 104
#define S_X1  0        // 32*232 = 7424
#define S_X2  7424     // 32*168 = 5376 -> 12800
#define S_X3A 12800    // 32*104 = 3328 -> 16128
#define S_X3B 16128    // 3328 -> 19456
#define S_X4  0        // overlay X1: [16][104] -> 1664
#define S_F2  1664     // overlay X1: [16][104] -> 3328
// dist tables (phase 0..1a only; dead before L1/L2A write their regions)
#define S_DA  7424     // real table [16][64][4] u -> 7424..11520  (in X2)
#define S_DI  12800    // img  table [16][64][4] u -> 12800..16896 (X3A + X3B head)

__device__ __forceinline__ ushort_t f2bf(float x) {
    __hip_bfloat16 hv = __float2bfloat16(x);
    return *reinterpret_cast<ushort_t*>(&hv);
}
__device__ __forceinline__ float bf2f(ushort_t h) {
    return __uint_as_float(((unsigned)h) << 16);
}

// ---- single fused weight+bias pack -----------------------------------------
__global__ __launch_bounds__(256)
void prep_all(const float* __restrict__ sW, const float* __restrict__ sb,
              const float* __restrict__ sg, const float* __restrict__ sbt,
              const float* __restrict__ aW, const float* __restrict__ ab,
              const float* __restrict__ ag, const float* __restrict__ abt,
              const float* __restrict__ bW, const float* __restrict__ bb_,
              const float* __restrict__ bg, const float* __restrict__ bbt,
              const float* __restrict__ lW, const float* __restrict__ lb,
              const float* __restrict__ cW, const float* __restrict__ cb,
              const float* __restrict__ cg, const float* __restrict__ cbt,
              const float* __restrict__ dW, const float* __restrict__ db,
              const float* __restrict__ dg, const float* __restrict__ dbt,
              const float* __restrict__ pW, const float* __restrict__ pb,
              const float* __restrict__ pg, const float* __restrict__ pbt,
              ushort_t* __restrict__ wsp) {
    int g = blockIdx.x * 256 + threadIdx.x;
    if (g >= 9280) return;
    if (g >= 8704) {                       // ---- bias table (576 floats) ----
        int idx = g - 8704;
        const float *B, *G, *BT; int m, has_bn;
        if (idx < 128)      { B=sb;  G=sg; BT=sbt; m=idx;       has_bn=1; }
        else if (idx < 192) { B=ab;  G=ag; BT=abt; m=idx-128;   has_bn=1; }
        else if (idx < 256) { B=bb_; G=bg; BT=bbt; m=idx-192;   has_bn=1; }
        else if (idx < 320) { B=lb;  G=lb; BT=lb;  m=idx-256;   has_bn=0; }
        else if (idx < 384) { B=cb;  G=cg; BT=cbt; m=idx-320;   has_bn=1; }
        else if (idx < 448) { B=db;  G=dg; BT=dbt; m=idx-384;   has_bn=1; }
        else                { B=pb;  G=pg; BT=pbt; m=idx-448;   has_bn=1; }
        ((float*)wsp)[FBF + idx] = has_bn ? fmaf(G[m], B[m], BT[m]) : B[m];
        return;
    }
    const float *W, *G;
    int in_c, KS, mode, has_bn, off;
    if (g < 3584)      {           W=sW; G=sg; in_c=195; KS=7; mode=1; has_bn=1; off=WP1;  }
    else if (g < 4608) { g -= 3584; W=aW; G=ag; in_c=128; KS=4; mode=0; has_bn=1; off=WP2A; }
    else if (g < 5120) { g -= 4608; W=bW; G=bg; in_c=64;  KS=2; mode=0; has_bn=1; off=WP2B; }
    else if (g < 5632) { g -= 5120; W=lW; G=lW; in_c=64;  KS=2; mode=0; has_bn=0; off=WLIN; }
    else if (g < 6656) { g -= 5632; W=cW; G=cg; in_c=128; KS=4; mode=0; has_bn=1; off=WC3A; }
    else if (g < 7168) { g -= 6656; W=dW; G=dg; in_c=64;  KS=2; mode=0; has_bn=1; off=WC3B; }
    else               { g -= 7168; W=pW; G=pg; in_c=67;  KS=3; mode=2; has_bn=1; off=WPN;  }

    int lane = g & 63, u = g >> 6, ks = u % KS, mt = u / KS;
    int m  = mt * 16 + (lane & 15);
    int k0 = ks * 32 + ((lane >> 4) << 3);
    float scale = has_bn ? G[m] : 1.0f;
    ushort_t o[8];
    #pragma unroll
    for (int i = 0; i < 8; ++i) {
        int k = k0 + i; float v = 0.0f;
        if (mode == 1) {          // L1: k = [repre 0..191 ; pts 192..194]
            if (k < 192)      v = W[m * 195 + 3 + k] * scale;
            else if (k < 195) v = W[m * 195 + (k - 192)] * scale;
        } else if (mode == 2) {   // PN2: k = [fused 0..63 ; pts 64..66]
            if (k < 64)       v = W[m * 67 + 3 + k] * scale;
            else if (k < 67)  v = W[m * 67 + (k - 64)] * scale;
        } else {
            if (k < in_c)     v = W[m * in_c + k] * scale;
        }
        o[i] = f2bf(v);
    }
    ushort4 lo, hi;
    lo.x = o[0]; lo.y = o[1]; lo.z = o[2]; lo.w = o[3];
    hi.x = o[4]; hi.y = o[5]; hi.z = o[6]; hi.w = o[7];
    int t = (((mt * KS + ks) * 64) + lane) * 8 + off;
    *(ushort4*)(wsp + t)     = lo;
    *(ushort4*)(wsp + t + 4) = hi;
}

template<int KS, int NTS>
__device__ __forceinline__ void mfma_tiles(const short8* __restrict__ WP,
                                           const float* __restrict__ fb,
                                           int mt, int nt0,
                                           const ushort_t* __restrict__ Xin, int sin,
                                           int lane, f32x4 acc[NTS]) {
    float4 b4 = *(const float4*)(fb + mt * 16 + ((lane >> 4) << 2));
    #pragma unroll
    for (int t = 0; t < NTS; ++t) acc[t] = (f32x4){b4.x, b4.y, b4.z, b4.w};
    #pragma unroll
    for (int ks = 0; ks < KS; ++ks) {
        short8 a = WP[(mt * KS + ks) * 64 + lane];
        #pragma unroll
        for (int t = 0; t < NTS; ++t) {
            const short8 bv = *(const short8*)(Xin + ((lane & 15) + (nt0 + t) * 16) * sin
                                               + ks * 32 + ((lane >> 4) << 3));
            acc[t] = __builtin_amdgcn_mfma_f32_16x16x32_bf16(a, bv, acc[t], 0, 0, 0);
        }
    }
}

template<int NTS>
__device__ __forceinline__ void epi_relu_lds(const f32x4 acc[NTS], int mt, int nt0,
                                             int h, int p, ushort_t* Xout, int sout) {
    int ch0 = mt * 16 + h * 4;
    #pragma unroll
    for (int t = 0; t < NTS; ++t) {
        int pt = p + (nt0 + t) * 16;
        ushort4 u;
        u.x = f2bf(fmaxf(acc[t].x, 0.f)); u.y = f2bf(fmaxf(acc[t].y, 0.f));
        u.z = f2bf(fmaxf(acc[t].z, 0.f)); u.w = f2bf(fmaxf(acc[t].w, 0.f));
        *(ushort4*)(Xout + pt * sout + ch0) = u;
    }
}

__device__ __forceinline__ float fold16(const f32x16 a) {
    float t0 = fminf(fminf(a[0], a[1]), a[2]);
    float t1 = fminf(fminf(a[3], a[4]), a[5]);
    float t2 = fminf(fminf(a[6], a[7]), a[8]);
    float t3 = fminf(fminf(a[9], a[10]), a[11]);
    float t4 = fminf(fminf(a[12], a[13]), a[14]);
    float s0 = fminf(fminf(t0, t1), t2);
    float s1 = fminf(fminf(t3, t4), a[15]);
    return fminf(s0, s1);
}

// dist for one point from precomputed tables: 4x ds_read_b64 + 4 MFMA
__device__ __forceinline__ void dist_point_tbl(const ushort_t* __restrict__ SM,
                                               int pt, int lane, float* __restrict__ DMIN) {
    const short8 zero8 = {0, 0, 0, 0, 0, 0, 0, 0};
    const int m32 = lane & 31;
    const int h2  = lane >> 5;
    short8 af[2], bfr[2];
    #pragma unroll
    for (int c = 0; c < 2; ++c) {
        ushort4 ra = *(const ushort4*)(SM + S_DA + (pt * 64 + c * 32 + m32) * 4);
        ushort4 rb = *(const ushort4*)(SM + S_DI + (pt * 64 + c * 32 + m32) * 4);
        short8 t = zero8;
        t[0] = (short)ra.x; t[1] = (short)ra.y; t[2] = (short)ra.z;
        t[3] = (short)ra.w; t[4] = (short)0x3F80;
        af[c] = h2 ? zero8 : t;
        short8 s = zero8;
        s[0] = (short)rb.x; s[1] = (short)rb.y; s[2] = (short)rb.z;
        s[3] = (short)0x3F80; s[4] = (short)rb.w;
        bfr[c] = h2 ? zero8 : s;
    }
    float dmin = 3.0e38f;
    #pragma unroll
    for (int kc = 0; kc < 2; ++kc) {
        #pragma unroll
        for (int lc = 0; lc < 2; ++lc) {
            f32x16 acc = {0.f,0.f,0.f,0.f,0.f,0.f,0.f,0.f,
                          0.f,0.f,0.f,0.f,0.f,0.f,0.f,0.f};
            acc = __builtin_amdgcn_mfma_f32_32x32x16_bf16(af[kc], bfr[lc], acc, 0, 0, 0);
            dmin = fminf(dmin, fold16(acc));
        }
    }
    #pragma unroll
    for (int off = 32; off > 0; off >>= 1)
        dmin = fminf(dmin, __shfl_xor(dmin, off, 64));
    if (lane == 0) DMIN[pt] = dmin;
}

__global__ __launch_bounds__(512, 8)
void fused_all(const float* __restrict__ img,   // [4][3][8192][64]
               const float* __restrict__ knn,   // [4][3][64][8192]
               const float* __restrict__ pts,   // [4][3][8192]
               const float* __restrict__ f2d,   // [4][64][8192]
               const float* __restrict__ fw1p, const float* __restrict__ fw2p,
               const float* __restrict__ fw3p,
               const ushort_t* __restrict__ wsp, float* __restrict__ out)
{
    __shared__ ushort_t SMEM[19456];
    __shared__ float DMIN[16];
    __shared__ float RBUF[3][4][16];

    const int tid  = threadIdx.x;
    const int wid  = __builtin_amdgcn_readfirstlane(tid >> 6);
    const int lane = tid & 63;
    const int p16  = lane & 15;
    const int h    = lane >> 4;
    const int b    = blockIdx.x >> 9;
    const int n0   = (blockIdx.x & 511) << 4;

    const int mt64 = wid & 3;
    const int nt1  = wid >> 2;

    const float* fbias = (const float*)wsp + FBF;
    f32x4 a2[2], a1[1];
    float fpre[4] = {0.f, 0.f, 0.f, 0.f};

    // ======= phase 0: stage knn/img + build centered dist tables ===========
    for (int e = tid; e < 32 * 29; e += 512) {           // X1 zero cols 195..223
        int r = e / 29, c = 195 + e % 29;
        SMEM[S_X1 + r * ST1 + c] = 0;
    }
    {   // knn -> rows 0..15 + DA table; thread = (pt, k-pair)
        int pt = tid & 15, kk = tid >> 4;                // kk 0..31
        int k0 = kk << 1;
        float pxv[3], rcn[2][3];
        #pragma unroll
        for (int c = 0; c < 3; ++c)
            pxv[c] = bf2f(f2bf(pts[((size_t)(b * 3 + c)) * N_PTS + n0 + pt]));
        #pragma unroll
        for (int c = 0; c < 3; ++c) {
            const float* base = knn + ((size_t)(b * 3 + c) * 64 + k0) * N_PTS + n0 + pt;
            ushort2 u;
            u.x = f2bf(base[0]);
            u.y = f2bf(base[(size_t)N_PTS]);
            *(ushort2*)(SMEM + S_X1 + pt * ST1 + c * 64 + k0) = u;
            rcn[0][c] = bf2f(u.x) - pxv[c];
            rcn[1][c] = bf2f(u.y) - pxv[c];
        }
        float r20 = fmaf(rcn[0][0], rcn[0][0], fmaf(rcn[0][1], rcn[0][1], rcn[0][2] * rcn[0][2]));
        float r21 = fmaf(rcn[1][0], rcn[1][0], fmaf(rcn[1][1], rcn[1][1], rcn[1][2] * rcn[1][2]));
        ushort4 lo, hi;
        lo.x = f2bf(-2.0f * rcn[0][0]); lo.y = f2bf(-2.0f * rcn[0][1]);
        lo.z = f2bf(-2.0f * rcn[0][2]); lo.w = f2bf(r20);
        hi.x = f2bf(-2.0f * rcn[1][0]); hi.y = f2bf(-2.0f * rcn[1][1]);
        hi.z = f2bf(-2.0f * rcn[1][2]); hi.w = f2bf(r21);
        *(ushort4*)(SMEM + S_DA + (pt * 64 + k0) * 4)     = lo;
        *(ushort4*)(SMEM + S_DA + (pt * 64 + k0) * 4 + 4) = hi;
    }
    {   // img -> rows 16..31 + DI table; thread = (pt, k-pair)
        int pt = tid >> 5, kk = tid & 31;
        int k0 = kk << 1;
        float pxv[3], icn[2][3];
        #pragma unroll
        for (int c = 0; c < 3; ++c)
            pxv[c] = bf2f(f2bf(pts[((size_t)(b * 3 + c)) * N_PTS + n0 + pt]));
        #pragma unroll
        for (int c = 0; c < 3; ++c) {
            float2 v = *(const float2*)(img + (((size_t)(b * 3 + c)) * N_PTS + n0 + pt) * 64 + k0);
            ushort2 u;
            u.x = f2bf(v.x); u.y = f2bf(v.y);
            *(ushort2*)(SMEM + S_X1 + (16 + pt) * ST1 + c * 64 + k0) = u;
            icn[0][c] = bf2f(u.x) - pxv[c];
            icn[1][c] = bf2f(u.y) - pxv[c];
        }
        float i20 = fmaf(icn[0][0], icn[0][0], fmaf(icn[0][1], icn[0][1], icn[0][2] * icn[0][2]));
        float i21 = fmaf(icn[1][0], icn[1][0], fmaf(icn[1][1], icn[1][1], icn[1][2] * icn[1][2]));
        ushort4 lo, hi;
        lo.x = f2bf(icn[0][0]); lo.y = f2bf(icn[0][1]);
        lo.z = f2bf(icn[0][2]); lo.w = f2bf(i20);
        hi.x = f2bf(icn[1][0]); hi.y = f2bf(icn[1][1]);
        hi.z = f2bf(icn[1][2]); hi.w = f2bf(i21);
        *(ushort4*)(SMEM + S_DI + (pt * 64 + k0) * 4)     = lo;
        *(ushort4*)(SMEM + S_DI + (pt * 64 + k0) * 4 + 4) = hi;
    }
    if (tid < 96) {                                      // pts ch 192..194, all rows
        int c = tid >> 5, r = tid & 31;
        SMEM[S_X1 + r * ST1 + 192 + c] = f2bf(pts[((size_t)(b * 3 + c)) * N_PTS + n0 + (r & 15)]);
    }
    __syncthreads();   // B1

    // ======= phase 1a: dist from tables (tables die after this) ============
    dist_point_tbl(SMEM, wid * 2, lane, DMIN);
    dist_point_tbl(SMEM, wid * 2 + 1, lane, DMIN);
    __syncthreads();   // B1.5

    // ======= phase 1b: L1 (32 rows) — writes X2 (over DA) ==================
    mfma_tiles<7, 2>((const short8*)(wsp + WP1), fbias + FB_L1, wid, 0,
                     SMEM + S_X1, ST1, lane, a2);
    epi_relu_lds<2>(a2, wid, 0, h, p16, SMEM + S_X2, ST2);
    __syncthreads();   // B2

    // ======= phase 2: L2A (32 rows) — writes X3A (over DI) =================
    mfma_tiles<4, 1>((const short8*)(wsp + WP2A), fbias + FB_2A, mt64, nt1,
                     SMEM + S_X2, ST2, lane, a1);
    epi_relu_lds<1>(a1, mt64, nt1, h, p16, SMEM + S_X3A, ST3);
    __syncthreads();   // B3

    // ======= phase 3: L2B + SHAL stores ====================================
    mfma_tiles<2, 1>((const short8*)(wsp + WP2B), fbias + FB_2B, mt64, nt1,
                     SMEM + S_X3A, ST3, lane, a1);
    {
        int ch0 = mt64 * 16 + h * 4;
        int row = p16 + nt1 * 16;
        float v0 = fmaxf(a1[0].x, 0.f), v1 = fmaxf(a1[0].y, 0.f);
        float v2 = fmaxf(a1[0].z, 0.f), v3 = fmaxf(a1[0].w, 0.f);
        ushort4 u;
        u.x = f2bf(v0); u.y = f2bf(v1); u.z = f2bf(v2); u.w = f2bf(v3);
        *(ushort4*)(SMEM + S_X3B + row * ST3 + ch0) = u;
        if (nt1 == 0) {
            size_t base = OUT_SHAL + ((size_t)(b * 64 + ch0)) * N_PTS + n0 + p16;
            out[base]             = v0;
            out[base + N_PTS]     = v1;
            out[base + 2 * N_PTS] = v2;
            out[base + 3 * N_PTS] = v3;
        }
    }
    __syncthreads();   // B4

    // ======= phase 4: LIN+cos (waves 0..3) | statics+preload (4..7) ========
    if (wid < 4) {
        f32x4 sv[2];
        mfma_tiles<2, 2>((const short8*)(wsp + WLIN), fbias + FB_LIN, wid, 0,
                         SMEM + S_X3B, ST3, lane, sv);
        float pn = sv[0].x * sv[1].x + sv[0].y * sv[1].y + sv[0].z * sv[1].z + sv[0].w * sv[1].w;
        float pr = sv[0].x * sv[0].x + sv[0].y * sv[0].y + sv[0].z * sv[0].z + sv[0].w * sv[0].w;
        float pi = sv[1].x * sv[1].x + sv[1].y * sv[1].y + sv[1].z * sv[1].z + sv[1].w * sv[1].w;
        pn += __shfl_xor(pn, 16, 64); pn += __shfl_xor(pn, 32, 64);
        pr += __shfl_xor(pr, 16, 64); pr += __shfl_xor(pr, 32, 64);
        pi += __shfl_xor(pi, 16, 64); pi += __shfl_xor(pi, 32, 64);
        if (lane < 16) {
            RBUF[0][wid][p16] = pn;
            RBUF[1][wid][p16] = pr;
            RBUF[2][wid][p16] = pi;
        }
    } else {
        int t256 = tid - 256;                            // 0..255
        int pt = t256 & 15, cg = t256 >> 4;
        #pragma unroll
        for (int r = 0; r < 4; ++r)
            fpre[r] = f2d[((size_t)(b * 64 + cg * 4 + r)) * N_PTS + n0 + pt];
        if (t256 < 48) {                                 // X4 pts ch64..66
            int c = t256 >> 4, r = t256 & 15;
            SMEM[S_X4 + r * ST3 + 64 + c] = f2bf(pts[((size_t)(b * 3 + c)) * N_PTS + n0 + r]);
        }
        for (int e = t256; e < 16 * 29; e += 256) {      // X4 zero cols 67..95
            int r = e / 29, c = 67 + e % 29;
            SMEM[S_X4 + r * ST3 + c] = 0;
        }
    }
    __syncthreads();   // B5

    // ======= phase 5: sim (redundant per-thread) + F2 fill =================
    if (wid >= 4) {
        int t256 = tid - 256;
        int pt = t256 & 15, cg = t256 >> 4;
        float num = 0.f, rr = 0.f, ii = 0.f;
        #pragma unroll
        for (int m = 0; m < 4; ++m) {
            num += RBUF[0][m][pt];
            rr  += RBUF[1][m][pt];
            ii  += RBUF[2][m][pt];
        }
        float den = fmaxf(sqrtf(rr) * sqrtf(ii), 1e-8f);
        float geo = expf(-(1.0f / fw1p[0]) * DMIN[pt]) + fw2p[0];
        float sim = (num / den) * geo;
        ushort4 u;
        u.x = f2bf(sim * fpre[0]); u.y = f2bf(sim * fpre[1]);
        u.z = f2bf(sim * fpre[2]); u.w = f2bf(sim * fpre[3]);
        *(ushort4*)(SMEM + S_F2 + pt * ST3 + cg * 4) = u;
        if (cg == 0) {
            out[OUT_SIM  + (size_t)b * N_PTS + n0 + pt] = sim;
            out[OUT_DSIM + (size_t)b * N_PTS + n0 + pt] = fw3p[0];
        }
    }
    __syncthreads();   // B6

    // ======= phase 6: C3A [X3B real ; F2] -> X3A rows 0..15 ================
    if (wid < 4) {
        const short8* W = (const short8*)(wsp + WC3A);
        float4 b4 = *(const float4*)(fbias + FB_3A + wid * 16 + (h << 2));
        f32x4 a = (f32x4){b4.x, b4.y, b4.z, b4.w};
        int row = p16 * ST3 + (h << 3);
        #pragma unroll
        for (int ks = 0; ks < 4; ++ks) {
            short8 aw = W[(wid * 4 + ks) * 64 + lane];
            const ushort_t* src = (ks < 2)
                ? (SMEM + S_X3B + row + ks * 32)
                : (SMEM + S_F2  + row + (ks - 2) * 32);
            a = __builtin_amdgcn_mfma_f32_16x16x32_bf16(aw, *(const short8*)src, a, 0, 0, 0);
        }
        a1[0] = a;
        epi_relu_lds<1>(a1, wid, 0, h, p16, SMEM + S_X3A, ST3);
    }
    __syncthreads();   // B7

    // ======= phase 7: C3B -> X4 ch0..63 rows 0..15 =========================
    if (wid < 4) {
        mfma_tiles<2, 1>((const short8*)(wsp + WC3B), fbias + FB_3B, wid, 0,
                         SMEM + S_X3A, ST3, lane, a1);
        epi_relu_lds<1>(a1, wid, 0, h, p16, SMEM + S_X4, ST3);
    }
    __syncthreads();   // B8

    // ======= phase 8: PN2 -> deeprealfeat ==================================
    mfma_tiles<3, 1>((const short8*)(wsp + WPN), fbias + FB_PN, wid, 0,
                     SMEM + S_X4, ST3, lane, a1);
    {
        int ch0 = wid * 16 + h * 4;
        size_t base = OUT_DEEP + ((size_t)(b * 128 + ch0)) * N_PTS + n0 + p16;
        out[base]             = fmaxf(a1[0].x, 0.f);
        out[base + N_PTS]     = fmaxf(a1[0].y, 0.f);
        out[base + 2 * N_PTS] = fmaxf(a1[0].z, 0.f);
        out[base + 3 * N_PTS] = fmaxf(a1[0].w, 0.f);
    }
}

extern "C" void kernel_launch(void* const* d_in, const int* in_sizes, int n_in,
                              void* d_out, int out_size, void* d_ws, size_t ws_size,
                              hipStream_t stream) {
    const float* img    = (const float*)d_in[0];
    const float* knn    = (const float*)d_in[1];
    const float* pts    = (const float*)d_in[2];
    const float* f2d    = (const float*)d_in[3];
    const float* sift_W = (const float*)d_in[4];
    const float* sift_b = (const float*)d_in[5];
    const float* sift_g = (const float*)d_in[6];
    const float* sift_bt= (const float*)d_in[7];
    const float* c2_W1  = (const float*)d_in[8];
    const float* c2_b1  = (const float*)d_in[9];
    const float* c2_g1  = (const float*)d_in[10];
    const float* c2_bt1 = (const float*)d_in[11];
    const float* c2_W2  = (const float*)d_in[12];
    const float* c2_b2  = (const float*)d_in[13];
    const float* c2_g2  = (const float*)d_in[14];
    const float* c2_bt2 = (const float*)d_in[15];
    const float* lin1_W = (const float*)d_in[16];
    const float* lin1_b = (const float*)d_in[17];
    const float* c3_W1  = (const float*)d_in[18];
    const float* c3_b1  = (const float*)d_in[19];
    const float* c3_g1  = (const float*)d_in[20];
    const float* c3_bt1 = (const float*)d_in[21];
    const float* c3_W2  = (const float*)d_in[22];
    const float* c3_b2  = (const float*)d_in[23];
    const float* c3_g2  = (const float*)d_in[24];
    const float* c3_bt2 = (const float*)d_in[25];
    const float* pn2_W  = (const float*)d_in[26];
    const float* pn2_b  = (const float*)d_in[27];
    const float* pn2_g  = (const float*)d_in[28];
    const float* pn2_bt = (const float*)d_in[29];
    const float* fw1    = (const float*)d_in[30];
    const float* fw2    = (const float*)d_in[31];
    const float* fw3    = (const float*)d_in[32];

    ushort_t* wsp = (ushort_t*)d_ws;
    float* out = (float*)d_out;

    prep_all<<<37, 256, 0, stream>>>(
        sift_W, sift_b, sift_g, sift_bt,
        c2_W1, c2_b1, c2_g1, c2_bt1,
        c2_W2, c2_b2, c2_g2, c2_bt2,
        lin1_W, lin1_b,
        c3_W1, c3_b1, c3_g1, c3_bt1,
        c3_W2, c3_b2, c3_g2, c3_bt2,
        pn2_W, pn2_b, pn2_g, pn2_bt,
        wsp);

    fused_all<<<2048, 512, 0, stream>>>(img, knn, pts, f2d, fw1, fw2, fw3, wsp, out);
}

// Round 13
// 40.331 us; speedup vs baseline: 5.7230x; 1.0107x over previous
//
#include <hip/hip_runtime.h>
#include <hip/hip_bf16.h>
#include <math.h>

// ===== round-12 structure + dist-table XOR swizzle =====
// Protected decisions (each regressed when changed):
//  - 16-point n-tiles (8-pt tiles: +73% HBM over-fetch, r9)
//  - 512-thread blocks, 1 tile per block (2-tile reg pipeline: scratch spill, r10)
//  - 16B-aligned LDS strides 232/168/104 (odd strides: misaligned b128, r7)
//  - dist tables built during staging (r12, -1.5us)

typedef __attribute__((ext_vector_type(8))) short short8;
typedef __attribute__((ext_vector_type(4))) float f32x4;
typedef __attribute__((ext_vector_type(16))) float f32x16;
typedef unsigned short ushort_t;

#define N_PTS 8192

// packed-weight offsets (ushort units), fragment order [(mt*KS+ks)*64+lane][8]
#define WP1   0       // MT8 KS7
#define WP2A  28672   // MT4 KS4
#define WP2B  36864   // MT4 KS2
#define WLIN  40960   // MT4 KS2
#define WC3A  45056   // MT4 KS4
#define WC3B  53248   // MT4 KS2
#define WPN   57344   // MT8 KS3 (end 69632)
#define FBF   34816   // float index into ws: bias table [576]
#define FB_L1 0
#define FB_2A 128
#define FB_2B 192
#define FB_LIN 256
#define FB_3A 320
#define FB_3B 384
#define FB_PN 448

// output float offsets
#define OUT_SIM  0
#define OUT_DSIM 32768
#define OUT_SHAL 65536
#define OUT_DEEP 2162688   // 65536 + 4*64*8192

// LDS carve (ushort units), 16 points => 32 rows (0..15 real, 16..31 img)
#define ST1 232
#define ST2 168
#define ST3 104
#define S_X1  0        // 32*232 = 7424
#define S_X2  7424     // 32*168 = 5376 -> 12800
#define S_X3A 12800    // 32*104 = 3328 -> 16128
#define S_X3B 16128    // 3328 -> 19456
#define S_X4  0        // overlay X1: [16][104] -> 1664
#define S_F2  1664     // overlay X1: [16][104] -> 3328
// dist tables (phase 0..1a only; dead before L1/L2A write their regions)
// layout: pt row = 256 ushorts; pair kk stored at slot (kk ^ (pt&7)) [bank swizzle]
#define S_DA  7424     // real table -> 7424..11520  (in X2)
#define S_DI  12800    // img  table -> 12800..16896 (X3A + X3B head)

__device__ __forceinline__ ushort_t f2bf(float x) {
    __hip_bfloat16 hv = __float2bfloat16(x);
    return *reinterpret_cast<ushort_t*>(&hv);
}
__device__ __forceinline__ float bf2f(ushort_t h) {
    return __uint_as_float(((unsigned)h) << 16);
}

// ---- single fused weight+bias pack -----------------------------------------
__global__ __launch_bounds__(256)
void prep_all(const float* __restrict__ sW, const float* __restrict__ sb,
              const float* __restrict__ sg, const float* __restrict__ sbt,
              const float* __restrict__ aW, const float* __restrict__ ab,
              const float* __restrict__ ag, const float* __restrict__ abt,
              const float* __restrict__ bW, const float* __restrict__ bb_,
              const float* __restrict__ bg, const float* __restrict__ bbt,
              const float* __restrict__ lW, const float* __restrict__ lb,
              const float* __restrict__ cW, const float* __restrict__ cb,
              const float* __restrict__ cg, const float* __restrict__ cbt,
              const float* __restrict__ dW, const float* __restrict__ db,
              const float* __restrict__ dg, const float* __restrict__ dbt,
              const float* __restrict__ pW, const float* __restrict__ pb,
              const float* __restrict__ pg, const float* __restrict__ pbt,
              ushort_t* __restrict__ wsp) {
    int g = blockIdx.x * 256 + threadIdx.x;
    if (g >= 9280) return;
    if (g >= 8704) {                       // ---- bias table (576 floats) ----
        int idx = g - 8704;
        const float *B, *G, *BT; int m, has_bn;
        if (idx < 128)      { B=sb;  G=sg; BT=sbt; m=idx;       has_bn=1; }
        else if (idx < 192) { B=ab;  G=ag; BT=abt; m=idx-128;   has_bn=1; }
        else if (idx < 256) { B=bb_; G=bg; BT=bbt; m=idx-192;   has_bn=1; }
        else if (idx < 320) { B=lb;  G=lb; BT=lb;  m=idx-256;   has_bn=0; }
        else if (idx < 384) { B=cb;  G=cg; BT=cbt; m=idx-320;   has_bn=1; }
        else if (idx < 448) { B=db;  G=dg; BT=dbt; m=idx-384;   has_bn=1; }
        else                { B=pb;  G=pg; BT=pbt; m=idx-448;   has_bn=1; }
        ((float*)wsp)[FBF + idx] = has_bn ? fmaf(G[m], B[m], BT[m]) : B[m];
        return;
    }
    const float *W, *G;
    int in_c, KS, mode, has_bn, off;
    if (g < 3584)      {           W=sW; G=sg; in_c=195; KS=7; mode=1; has_bn=1; off=WP1;  }
    else if (g < 4608) { g -= 3584; W=aW; G=ag; in_c=128; KS=4; mode=0; has_bn=1; off=WP2A; }
    else if (g < 5120) { g -= 4608; W=bW; G=bg; in_c=64;  KS=2; mode=0; has_bn=1; off=WP2B; }
    else if (g < 5632) { g -= 5120; W=lW; G=lW; in_c=64;  KS=2; mode=0; has_bn=0; off=WLIN; }
    else if (g < 6656) { g -= 5632; W=cW; G=cg; in_c=128; KS=4; mode=0; has_bn=1; off=WC3A; }
    else if (g < 7168) { g -= 6656; W=dW; G=dg; in_c=64;  KS=2; mode=0; has_bn=1; off=WC3B; }
    else               { g -= 7168; W=pW; G=pg; in_c=67;  KS=3; mode=2; has_bn=1; off=WPN;  }

    int lane = g & 63, u = g >> 6, ks = u % KS, mt = u / KS;
    int m  = mt * 16 + (lane & 15);
    int k0 = ks * 32 + ((lane >> 4) << 3);
    float scale = has_bn ? G[m] : 1.0f;
    ushort_t o[8];
    #pragma unroll
    for (int i = 0; i < 8; ++i) {
        int k = k0 + i; float v = 0.0f;
        if (mode == 1) {          // L1: k = [repre 0..191 ; pts 192..194]
            if (k < 192)      v = W[m * 195 + 3 + k] * scale;
            else if (k < 195) v = W[m * 195 + (k - 192)] * scale;
        } else if (mode == 2) {   // PN2: k = [fused 0..63 ; pts 64..66]
            if (k < 64)       v = W[m * 67 + 3 + k] * scale;
            else if (k < 67)  v = W[m * 67 + (k - 64)] * scale;
        } else {
            if (k < in_c)     v = W[m * in_c + k] * scale;
        }
        o[i] = f2bf(v);
    }
    ushort4 lo, hi;
    lo.x = o[0]; lo.y = o[1]; lo.z = o[2]; lo.w = o[3];
    hi.x = o[4]; hi.y = o[5]; hi.z = o[6]; hi.w = o[7];
    int t = (((mt * KS + ks) * 64) + lane) * 8 + off;
    *(ushort4*)(wsp + t)     = lo;
    *(ushort4*)(wsp + t + 4) = hi;
}

template<int KS, int NTS>
__device__ __forceinline__ void mfma_tiles(const short8* __restrict__ WP,
                                           const float* __restrict__ fb,
                                           int mt, int nt0,
                                           const ushort_t* __restrict__ Xin, int sin,
                                           int lane, f32x4 acc[NTS]) {
    float4 b4 = *(const float4*)(fb + mt * 16 + ((lane >> 4) << 2));
    #pragma unroll
    for (int t = 0; t < NTS; ++t) acc[t] = (f32x4){b4.x, b4.y, b4.z, b4.w};
    #pragma unroll
    for (int ks = 0; ks < KS; ++ks) {
        short8 a = WP[(mt * KS + ks) * 64 + lane];
        #pragma unroll
        for (int t = 0; t < NTS; ++t) {
            const short8 bv = *(const short8*)(Xin + ((lane & 15) + (nt0 + t) * 16) * sin
                                               + ks * 32 + ((lane >> 4) << 3));
            acc[t] = __builtin_amdgcn_mfma_f32_16x16x32_bf16(a, bv, acc[t], 0, 0, 0);
        }
    }
}

template<int NTS>
__device__ __forceinline__ void epi_relu_lds(const f32x4 acc[NTS], int mt, int nt0,
                                             int h, int p, ushort_t* Xout, int sout) {
    int ch0 = mt * 16 + h * 4;
    #pragma unroll
    for (int t = 0; t < NTS; ++t) {
        int pt = p + (nt0 + t) * 16;
        ushort4 u;
        u.x = f2bf(fmaxf(acc[t].x, 0.f)); u.y = f2bf(fmaxf(acc[t].y, 0.f));
        u.z = f2bf(fmaxf(acc[t].z, 0.f)); u.w = f2bf(fmaxf(acc[t].w, 0.f));
        *(ushort4*)(Xout + pt * sout + ch0) = u;
    }
}

__device__ __forceinline__ float fold16(const f32x16 a) {
    float t0 = fminf(fminf(a[0], a[1]), a[2]);
    float t1 = fminf(fminf(a[3], a[4]), a[5]);
    float t2 = fminf(fminf(a[6], a[7]), a[8]);
    float t3 = fminf(fminf(a[9], a[10]), a[11]);
    float t4 = fminf(fminf(a[12], a[13]), a[14]);
    float s0 = fminf(fminf(t0, t1), t2);
    float s1 = fminf(fminf(t3, t4), a[15]);
    return fminf(s0, s1);
}

// dist for one point from swizzled tables: 4x ds_read_b64 + 4 MFMA
__device__ __forceinline__ void dist_point_tbl(const ushort_t* __restrict__ SM,
                                               int pt, int lane, float* __restrict__ DMIN) {
    const short8 zero8 = {0, 0, 0, 0, 0, 0, 0, 0};
    const int m32 = lane & 31;
    const int h2  = lane >> 5;
    const int sw  = pt & 7;
    short8 af[2], bfr[2];
    #pragma unroll
    for (int c = 0; c < 2; ++c) {
        int k   = c * 32 + m32;
        int idx = pt * 256 + ((k >> 1) ^ sw) * 8 + (k & 1) * 4;
        ushort4 ra = *(const ushort4*)(SM + S_DA + idx);
        ushort4 rb = *(const ushort4*)(SM + S_DI + idx);
        short8 t = zero8;
        t[0] = (short)ra.x; t[1] = (short)ra.y; t[2] = (short)ra.z;
        t[3] = (short)ra.w; t[4] = (short)0x3F80;
        af[c] = h2 ? zero8 : t;
        short8 s = zero8;
        s[0] = (short)rb.x; s[1] = (short)rb.y; s[2] = (short)rb.z;
        s[3] = (short)0x3F80; s[4] = (short)rb.w;
        bfr[c] = h2 ? zero8 : s;
    }
    float dmin = 3.0e38f;
    #pragma unroll
    for (int kc = 0; kc < 2; ++kc) {
        #pragma unroll
        for (int lc = 0; lc < 2; ++lc) {
            f32x16 acc = {0.f,0.f,0.f,0.f,0.f,0.f,0.f,0.f,
                          0.f,0.f,0.f,0.f,0.f,0.f,0.f,0.f};
            acc = __builtin_amdgcn_mfma_f32_32x32x16_bf16(af[kc], bfr[lc], acc, 0, 0, 0);
            dmin = fminf(dmin, fold16(acc));
        }
    }
    #pragma unroll
    for (int off = 32; off > 0; off >>= 1)
        dmin = fminf(dmin, __shfl_xor(dmin, off, 64));
    if (lane == 0) DMIN[pt] = dmin;
}

__global__ __launch_bounds__(512, 8)
void fused_all(const float* __restrict__ img,   // [4][3][8192][64]
               const float* __restrict__ knn,   // [4][3][64][8192]
               const float* __restrict__ pts,   // [4][3][8192]
               const float* __restrict__ f2d,   // [4][64][8192]
               const float* __restrict__ fw1p, const float* __restrict__ fw2p,
               const float* __restrict__ fw3p,
               const ushort_t* __restrict__ wsp, float* __restrict__ out)
{
    __shared__ ushort_t SMEM[19456];
    __shared__ float DMIN[16];
    __shared__ float RBUF[3][4][16];

    const int tid  = threadIdx.x;
    const int wid  = __builtin_amdgcn_readfirstlane(tid >> 6);
    const int lane = tid & 63;
    const int p16  = lane & 15;
    const int h    = lane >> 4;
    const int b    = blockIdx.x >> 9;
    const int n0   = (blockIdx.x & 511) << 4;

    const int mt64 = wid & 3;
    const int nt1  = wid >> 2;

    const float* fbias = (const float*)wsp + FBF;
    f32x4 a2[2], a1[1];
    float fpre[4] = {0.f, 0.f, 0.f, 0.f};

    // ======= phase 0: stage knn/img + build centered dist tables ===========
    for (int e = tid; e < 32 * 29; e += 512) {           // X1 zero cols 195..223
        int r = e / 29, c = 195 + e % 29;
        SMEM[S_X1 + r * ST1 + c] = 0;
    }
    {   // knn -> rows 0..15 + DA table; thread = (pt, k-pair)
        int pt = tid & 15, kk = tid >> 4;                // kk 0..31
        int k0 = kk << 1;
        int kx = (kk ^ (pt & 7)) << 1;                   // swizzled pair slot
        float pxv[3], rcn[2][3];
        #pragma unroll
        for (int c = 0; c < 3; ++c)
            pxv[c] = bf2f(f2bf(pts[((size_t)(b * 3 + c)) * N_PTS + n0 + pt]));
        #pragma unroll
        for (int c = 0; c < 3; ++c) {
            const float* base = knn + ((size_t)(b * 3 + c) * 64 + k0) * N_PTS + n0 + pt;
            ushort2 u;
            u.x = f2bf(base[0]);
            u.y = f2bf(base[(size_t)N_PTS]);
            *(ushort2*)(SMEM + S_X1 + pt * ST1 + c * 64 + k0) = u;
            rcn[0][c] = bf2f(u.x) - pxv[c];
            rcn[1][c] = bf2f(u.y) - pxv[c];
        }
        float r20 = fmaf(rcn[0][0], rcn[0][0], fmaf(rcn[0][1], rcn[0][1], rcn[0][2] * rcn[0][2]));
        float r21 = fmaf(rcn[1][0], rcn[1][0], fmaf(rcn[1][1], rcn[1][1], rcn[1][2] * rcn[1][2]));
        ushort4 lo, hi;
        lo.x = f2bf(-2.0f * rcn[0][0]); lo.y = f2bf(-2.0f * rcn[0][1]);
        lo.z = f2bf(-2.0f * rcn[0][2]); lo.w = f2bf(r20);
        hi.x = f2bf(-2.0f * rcn[1][0]); hi.y = f2bf(-2.0f * rcn[1][1]);
        hi.z = f2bf(-2.0f * rcn[1][2]); hi.w = f2bf(r21);
        *(ushort4*)(SMEM + S_DA + (pt * 64 + kx) * 4)     = lo;
        *(ushort4*)(SMEM + S_DA + (pt * 64 + kx) * 4 + 4) = hi;
    }
    {   // img -> rows 16..31 + DI table; thread = (pt, k-pair)
        int pt = tid >> 5, kk = tid & 31;
        int k0 = kk << 1;
        int kx = (kk ^ (pt & 7)) << 1;                   // swizzled pair slot
        float pxv[3], icn[2][3];
        #pragma unroll
        for (int c = 0; c < 3; ++c)
            pxv[c] = bf2f(f2bf(pts[((size_t)(b * 3 + c)) * N_PTS + n0 + pt]));
        #pragma unroll
        for (int c = 0; c < 3; ++c) {
            float2 v = *(const float2*)(img + (((size_t)(b * 3 + c)) * N_PTS + n0 + pt) * 64 + k0);
            ushort2 u;
            u.x = f2bf(v.x); u.y = f2bf(v.y);
            *(ushort2*)(SMEM + S_X1 + (16 + pt) * ST1 + c * 64 + k0) = u;
            icn[0][c] = bf2f(u.x) - pxv[c];
            icn[1][c] = bf2f(u.y) - pxv[c];
        }
        float i20 = fmaf(icn[0][0], icn[0][0], fmaf(icn[0][1], icn[0][1], icn[0][2] * icn[0][2]));
        float i21 = fmaf(icn[1][0], icn[1][0], fmaf(icn[1][1], icn[1][1], icn[1][2] * icn[1][2]));
        ushort4 lo, hi;
        lo.x = f2bf(icn[0][0]); lo.y = f2bf(icn[0][1]);
        lo.z = f2bf(icn[0][2]); lo.w = f2bf(i20);
        hi.x = f2bf(icn[1][0]); hi.y = f2bf(icn[1][1]);
        hi.z = f2bf(icn[1][2]); hi.w = f2bf(i21);
        *(ushort4*)(SMEM + S_DI + (pt * 64 + kx) * 4)     = lo;
        *(ushort4*)(SMEM + S_DI + (pt * 64 + kx) * 4 + 4) = hi;
    }
    if (tid < 96) {                                      // pts ch 192..194, all rows
        int c = tid >> 5, r = tid & 31;
        SMEM[S_X1 + r * ST1 + 192 + c] = f2bf(pts[((size_t)(b * 3 + c)) * N_PTS + n0 + (r & 15)]);
    }
    __syncthreads();   // B1

    // ======= phase 1a: dist from tables (tables die after this) ============
    dist_point_tbl(SMEM, wid * 2, lane, DMIN);
    dist_point_tbl(SMEM, wid * 2 + 1, lane, DMIN);
    __syncthreads();   // B1.5

    // ======= phase 1b: L1 (32 rows) — writes X2 (over DA) ==================
    mfma_tiles<7, 2>((const short8*)(wsp + WP1), fbias + FB_L1, wid, 0,
                     SMEM + S_X1, ST1, lane, a2);
    epi_relu_lds<2>(a2, wid, 0, h, p16, SMEM + S_X2, ST2);
    __syncthreads();   // B2

    // ======= phase 2: L2A (32 rows) — writes X3A (over DI) =================
    mfma_tiles<4, 1>((const short8*)(wsp + WP2A), fbias + FB_2A, mt64, nt1,
                     SMEM + S_X2, ST2, lane, a1);
    epi_relu_lds<1>(a1, mt64, nt1, h, p16, SMEM + S_X3A, ST3);
    __syncthreads();   // B3

    // ======= phase 3: L2B + SHAL stores ====================================
    mfma_tiles<2, 1>((const short8*)(wsp + WP2B), fbias + FB_2B, mt64, nt1,
                     SMEM + S_X3A, ST3, lane, a1);
    {
        int ch0 = mt64 * 16 + h * 4;
        int row = p16 + nt1 * 16;
        float v0 = fmaxf(a1[0].x, 0.f), v1 = fmaxf(a1[0].y, 0.f);
        float v2 = fmaxf(a1[0].z, 0.f), v3 = fmaxf(a1[0].w, 0.f);
        ushort4 u;
        u.x = f2bf(v0); u.y = f2bf(v1); u.z = f2bf(v2); u.w = f2bf(v3);
        *(ushort4*)(SMEM + S_X3B + row * ST3 + ch0) = u;
        if (nt1 == 0) {
            size_t base = OUT_SHAL + ((size_t)(b * 64 + ch0)) * N_PTS + n0 + p16;
            out[base]             = v0;
            out[base + N_PTS]     = v1;
            out[base + 2 * N_PTS] = v2;
            out[base + 3 * N_PTS] = v3;
        }
    }
    __syncthreads();   // B4

    // ======= phase 4: LIN+cos (waves 0..3) | statics+preload (4..7) ========
    if (wid < 4) {
        f32x4 sv[2];
        mfma_tiles<2, 2>((const short8*)(wsp + WLIN), fbias + FB_LIN, wid, 0,
                         SMEM + S_X3B, ST3, lane, sv);
        float pn = sv[0].x * sv[1].x + sv[0].y * sv[1].y + sv[0].z * sv[1].z + sv[0].w * sv[1].w;
        float pr = sv[0].x * sv[0].x + sv[0].y * sv[0].y + sv[0].z * sv[0].z + sv[0].w * sv[0].w;
        float pi = sv[1].x * sv[1].x + sv[1].y * sv[1].y + sv[1].z * sv[1].z + sv[1].w * sv[1].w;
        pn += __shfl_xor(pn, 16, 64); pn += __shfl_xor(pn, 32, 64);
        pr += __shfl_xor(pr, 16, 64); pr += __shfl_xor(pr, 32, 64);
        pi += __shfl_xor(pi, 16, 64); pi += __shfl_xor(pi, 32, 64);
        if (lane < 16) {
            RBUF[0][wid][p16] = pn;
            RBUF[1][wid][p16] = pr;
            RBUF[2][wid][p16] = pi;
        }
    } else {
        int t256 = tid - 256;                            // 0..255
        int pt = t256 & 15, cg = t256 >> 4;
        #pragma unroll
        for (int r = 0; r < 4; ++r)
            fpre[r] = f2d[((size_t)(b * 64 + cg * 4 + r)) * N_PTS + n0 + pt];
        if (t256 < 48) {                                 // X4 pts ch64..66
            int c = t256 >> 4, r = t256 & 15;
            SMEM[S_X4 + r * ST3 + 64 + c] = f2bf(pts[((size_t)(b * 3 + c)) * N_PTS + n0 + r]);
        }
        for (int e = t256; e < 16 * 29; e += 256) {      // X4 zero cols 67..95
            int r = e / 29, c = 67 + e % 29;
            SMEM[S_X4 + r * ST3 + c] = 0;
        }
    }
    __syncthreads();   // B5

    // ======= phase 5: sim (redundant per-thread) + F2 fill =================
    if (wid >= 4) {
        int t256 = tid - 256;
        int pt = t256 & 15, cg = t256 >> 4;
        float num = 0.f, rr = 0.f, ii = 0.f;
        #pragma unroll
        for (int m = 0; m < 4; ++m) {
            num += RBUF[0][m][pt];
            rr  += RBUF[1][m][pt];
            ii  += RBUF[2][m][pt];
        }
        float den = fmaxf(sqrtf(rr) * sqrtf(ii), 1e-8f);
        float geo = expf(-(1.0f / fw1p[0]) * DMIN[pt]) + fw2p[0];
        float sim = (num / den) * geo;
        ushort4 u;
        u.x = f2bf(sim * fpre[0]); u.y = f2bf(sim * fpre[1]);
        u.z = f2bf(sim * fpre[2]); u.w = f2bf(sim * fpre[3]);
        *(ushort4*)(SMEM + S_F2 + pt * ST3 + cg * 4) = u;
        if (cg == 0) {
            out[OUT_SIM  + (size_t)b * N_PTS + n0 + pt] = sim;
            out[OUT_DSIM + (size_t)b * N_PTS + n0 + pt] = fw3p[0];
        }
    }
    __syncthreads();   // B6

    // ======= phase 6: C3A [X3B real ; F2] -> X3A rows 0..15 ================
    if (wid < 4) {
        const short8* W = (const short8*)(wsp + WC3A);
        float4 b4 = *(const float4*)(fbias + FB_3A + wid * 16 + (h << 2));
        f32x4 a = (f32x4){b4.x, b4.y, b4.z, b4.w};
        int row = p16 * ST3 + (h << 3);
        #pragma unroll
        for (int ks = 0; ks < 4; ++ks) {
            short8 aw = W[(wid * 4 + ks) * 64 + lane];
            const ushort_t* src = (ks < 2)
                ? (SMEM + S_X3B + row + ks * 32)
                : (SMEM + S_F2  + row + (ks - 2) * 32);
            a = __builtin_amdgcn_mfma_f32_16x16x32_bf16(aw, *(const short8*)src, a, 0, 0, 0);
        }
        a1[0] = a;
        epi_relu_lds<1>(a1, wid, 0, h, p16, SMEM + S_X3A, ST3);
    }
    __syncthreads();   // B7

    // ======= phase 7: C3B -> X4 ch0..63 rows 0..15 =========================
    if (wid < 4) {
        mfma_tiles<2, 1>((const short8*)(wsp + WC3B), fbias + FB_3B, wid, 0,
                         SMEM + S_X3A, ST3, lane, a1);
        epi_relu_lds<1>(a1, wid, 0, h, p16, SMEM + S_X4, ST3);
    }
    __syncthreads();   // B8

    // ======= phase 8: PN2 -> deeprealfeat ==================================
    mfma_tiles<3, 1>((const short8*)(wsp + WPN), fbias + FB_PN, wid, 0,
                     SMEM + S_X4, ST3, lane, a1);
    {
        int ch0 = wid * 16 + h * 4;
        size_t base = OUT_DEEP + ((size_t)(b * 128 + ch0)) * N_PTS + n0 + p16;
        out[base]             = fmaxf(a1[0].x, 0.f);
        out[base + N_PTS]     = fmaxf(a1[0].y, 0.f);
        out[base + 2 * N_PTS] = fmaxf(a1[0].z, 0.f);
        out[base + 3 * N_PTS] = fmaxf(a1[0].w, 0.f);
    }
}

extern "C" void kernel_launch(void* const* d_in, const int* in_sizes, int n_in,
                              void* d_out, int out_size, void* d_ws, size_t ws_size,
                              hipStream_t stream) {
    const float* img    = (const float*)d_in[0];
    const float* knn    = (const float*)d_in[1];
    const float* pts    = (const float*)d_in[2];
    const float* f2d    = (const float*)d_in[3];
    const float* sift_W = (const float*)d_in[4];
    const float* sift_b = (const float*)d_in[5];
    const float* sift_g = (const float*)d_in[6];
    const float* sift_bt= (const float*)d_in[7];
    const float* c2_W1  = (const float*)d_in[8];
    const float* c2_b1  = (const float*)d_in[9];
    const float* c2_g1  = (const float*)d_in[10];
    const float* c2_bt1 = (const float*)d_in[11];
    const float* c2_W2  = (const float*)d_in[12];
    const float* c2_b2  = (const float*)d_in[13];
    const float* c2_g2  = (const float*)d_in[14];
    const float* c2_bt2 = (const float*)d_in[15];
    const float* lin1_W = (const float*)d_in[16];
    const float* lin1_b = (const float*)d_in[17];
    const float* c3_W1  = (const float*)d_in[18];
    const float* c3_b1  = (const float*)d_in[19];
    const float* c3_g1  = (const float*)d_in[20];
    const float* c3_bt1 = (const float*)d_in[21];
    const float* c3_W2  = (const float*)d_in[22];
    const float* c3_b2  = (const float*)d_in[23];
    const float* c3_g2  = (const float*)d_in[24];
    const float* c3_bt2 = (const float*)d_in[25];
    const float* pn2_W  = (const float*)d_in[26];
    const float* pn2_b  = (const float*)d_in[27];
    const float* pn2_g  = (const float*)d_in[28];
    const float* pn2_bt = (const float*)d_in[29];
    const float* fw1    = (const float*)d_in[30];
    const float* fw2    = (const float*)d_in[31];
    const float* fw3    = (const float*)d_in[32];

    ushort_t* wsp = (ushort_t*)d_ws;
    float* out = (float*)d_out;

    prep_all<<<37, 256, 0, stream>>>(
        sift_W, sift_b, sift_g, sift_bt,
        c2_W1, c2_b1, c2_g1, c2_bt1,
        c2_W2, c2_b2, c2_g2, c2_bt2,
        lin1_W, lin1_b,
        c3_W1, c3_b1, c3_g1, c3_bt1,
        c3_W2, c3_b2, c3_g2, c3_bt2,
        pn2_W, pn2_b, pn2_g, pn2_bt,
        wsp);

    fused_all<<<2048, 512, 0, stream>>>(img, knn, pts, f2d, fw1, fw2, fw3, wsp, out);
}

// Round 14
// 39.980 us; speedup vs baseline: 5.7732x; 1.0088x over previous
//
#include <hip/hip_runtime.h>
#include <hip/hip_bf16.h>
#include <math.h>

// ===== round-13 structure + C3A K-split across phases 5/6 =====
// Protected decisions (each regressed when changed):
//  - 16-point n-tiles (8-pt tiles: +73% HBM over-fetch, r9)
//  - 512-thread blocks, 1 tile per block (2-tile reg pipeline: scratch spill, r10)
//  - 16B-aligned LDS strides 232/168/104 (odd strides: misaligned b128, r7)
//  - dist tables built during staging (r12), XOR-swizzled writes (r13)

typedef __attribute__((ext_vector_type(8))) short short8;
typedef __attribute__((ext_vector_type(4))) float f32x4;
typedef __attribute__((ext_vector_type(16))) float f32x16;
typedef unsigned short ushort_t;

#define N_PTS 8192

// packed-weight offsets (ushort units), fragment order [(mt*KS+ks)*64+lane][8]
#define WP1   0       // MT8 KS7
#define WP2A  28672   // MT4 KS4
#define WP2B  36864   // MT4 KS2
#define WLIN  40960   // MT4 KS2
#define WC3A  45056   // MT4 KS4
#define WC3B  53248   // MT4 KS2
#define WPN   57344   // MT8 KS3 (end 69632)
#define FBF   34816   // float index into ws: bias table [576]
#define FB_L1 0
#define FB_2A 128
#define FB_2B 192
#define FB_LIN 256
#define FB_3A 320
#define FB_3B 384
#define FB_PN 448

// output float offsets
#define OUT_SIM  0
#define OUT_DSIM 32768
#define OUT_SHAL 65536
#define OUT_DEEP 2162688   // 65536 + 4*64*8192

// LDS carve (ushort units), 16 points => 32 rows (0..15 real, 16..31 img)
#define ST1 232
#define ST2 168
#define ST3 104
#define S_X1  0        // 32*232 = 7424
#define S_X2  7424     // 32*168 = 5376 -> 12800
#define S_X3A 12800    // 32*104 = 3328 -> 16128
#define S_X3B 16128    // 3328 -> 19456
#define S_X4  0        // overlay X1: [16][104] -> 1664
#define S_F2  1664     // overlay X1: [16][104] -> 3328
// dist tables (phase 0..1a only; dead before L1/L2A write their regions)
// layout: pt row = 256 ushorts; pair kk stored at slot (kk ^ (pt&7)) [bank swizzle]
#define S_DA  7424     // real table -> 7424..11520  (in X2)
#define S_DI  12800    // img  table -> 12800..16896 (X3A + X3B head)

__device__ __forceinline__ ushort_t f2bf(float x) {
    __hip_bfloat16 hv = __float2bfloat16(x);
    return *reinterpret_cast<ushort_t*>(&hv);
}
__device__ __forceinline__ float bf2f(ushort_t h) {
    return __uint_as_float(((unsigned)h) << 16);
}

// ---- single fused weight+bias pack -----------------------------------------
__global__ __launch_bounds__(256)
void prep_all(const float* __restrict__ sW, const float* __restrict__ sb,
              const float* __restrict__ sg, const float* __restrict__ sbt,
              const float* __restrict__ aW, const float* __restrict__ ab,
              const float* __restrict__ ag, const float* __restrict__ abt,
              const float* __restrict__ bW, const float* __restrict__ bb_,
              const float* __restrict__ bg, const float* __restrict__ bbt,
              const float* __restrict__ lW, const float* __restrict__ lb,
              const float* __restrict__ cW, const float* __restrict__ cb,
              const float* __restrict__ cg, const float* __restrict__ cbt,
              const float* __restrict__ dW, const float* __restrict__ db,
              const float* __restrict__ dg, const float* __restrict__ dbt,
              const float* __restrict__ pW, const float* __restrict__ pb,
              const float* __restrict__ pg, const float* __restrict__ pbt,
              ushort_t* __restrict__ wsp) {
    int g = blockIdx.x * 256 + threadIdx.x;
    if (g >= 9280) return;
    if (g >= 8704) {                       // ---- bias table (576 floats) ----
        int idx = g - 8704;
        const float *B, *G, *BT; int m, has_bn;
        if (idx < 128)      { B=sb;  G=sg; BT=sbt; m=idx;       has_bn=1; }
        else if (idx < 192) { B=ab;  G=ag; BT=abt; m=idx-128;   has_bn=1; }
        else if (idx < 256) { B=bb_; G=bg; BT=bbt; m=idx-192;   has_bn=1; }
        else if (idx < 320) { B=lb;  G=lb; BT=lb;  m=idx-256;   has_bn=0; }
        else if (idx < 384) { B=cb;  G=cg; BT=cbt; m=idx-320;   has_bn=1; }
        else if (idx < 448) { B=db;  G=dg; BT=dbt; m=idx-384;   has_bn=1; }
        else                { B=pb;  G=pg; BT=pbt; m=idx-448;   has_bn=1; }
        ((float*)wsp)[FBF + idx] = has_bn ? fmaf(G[m], B[m], BT[m]) : B[m];
        return;
    }
    const float *W, *G;
    int in_c, KS, mode, has_bn, off;
    if (g < 3584)      {           W=sW; G=sg; in_c=195; KS=7; mode=1; has_bn=1; off=WP1;  }
    else if (g < 4608) { g -= 3584; W=aW; G=ag; in_c=128; KS=4; mode=0; has_bn=1; off=WP2A; }
    else if (g < 5120) { g -= 4608; W=bW; G=bg; in_c=64;  KS=2; mode=0; has_bn=1; off=WP2B; }
    else if (g < 5632) { g -= 5120; W=lW; G=lW; in_c=64;  KS=2; mode=0; has_bn=0; off=WLIN; }
    else if (g < 6656) { g -= 5632; W=cW; G=cg; in_c=128; KS=4; mode=0; has_bn=1; off=WC3A; }
    else if (g < 7168) { g -= 6656; W=dW; G=dg; in_c=64;  KS=2; mode=0; has_bn=1; off=WC3B; }
    else               { g -= 7168; W=pW; G=pg; in_c=67;  KS=3; mode=2; has_bn=1; off=WPN;  }

    int lane = g & 63, u = g >> 6, ks = u % KS, mt = u / KS;
    int m  = mt * 16 + (lane & 15);
    int k0 = ks * 32 + ((lane >> 4) << 3);
    float scale = has_bn ? G[m] : 1.0f;
    ushort_t o[8];
    #pragma unroll
    for (int i = 0; i < 8; ++i) {
        int k = k0 + i; float v = 0.0f;
        if (mode == 1) {          // L1: k = [repre 0..191 ; pts 192..194]
            if (k < 192)      v = W[m * 195 + 3 + k] * scale;
            else if (k < 195) v = W[m * 195 + (k - 192)] * scale;
        } else if (mode == 2) {   // PN2: k = [fused 0..63 ; pts 64..66]
            if (k < 64)       v = W[m * 67 + 3 + k] * scale;
            else if (k < 67)  v = W[m * 67 + (k - 64)] * scale;
        } else {
            if (k < in_c)     v = W[m * in_c + k] * scale;
        }
        o[i] = f2bf(v);
    }
    ushort4 lo, hi;
    lo.x = o[0]; lo.y = o[1]; lo.z = o[2]; lo.w = o[3];
    hi.x = o[4]; hi.y = o[5]; hi.z = o[6]; hi.w = o[7];
    int t = (((mt * KS + ks) * 64) + lane) * 8 + off;
    *(ushort4*)(wsp + t)     = lo;
    *(ushort4*)(wsp + t + 4) = hi;
}

template<int KS, int NTS>
__device__ __forceinline__ void mfma_tiles(const short8* __restrict__ WP,
                                           const float* __restrict__ fb,
                                           int mt, int nt0,
                                           const ushort_t* __restrict__ Xin, int sin,
                                           int lane, f32x4 acc[NTS]) {
    float4 b4 = *(const float4*)(fb + mt * 16 + ((lane >> 4) << 2));
    #pragma unroll
    for (int t = 0; t < NTS; ++t) acc[t] = (f32x4){b4.x, b4.y, b4.z, b4.w};
    #pragma unroll
    for (int ks = 0; ks < KS; ++ks) {
        short8 a = WP[(mt * KS + ks) * 64 + lane];
        #pragma unroll
        for (int t = 0; t < NTS; ++t) {
            const short8 bv = *(const short8*)(Xin + ((lane & 15) + (nt0 + t) * 16) * sin
                                               + ks * 32 + ((lane >> 4) << 3));
            acc[t] = __builtin_amdgcn_mfma_f32_16x16x32_bf16(a, bv, acc[t], 0, 0, 0);
        }
    }
}

template<int NTS>
__device__ __forceinline__ void epi_relu_lds(const f32x4 acc[NTS], int mt, int nt0,
                                             int h, int p, ushort_t* Xout, int sout) {
    int ch0 = mt * 16 + h * 4;
    #pragma unroll
    for (int t = 0; t < NTS; ++t) {
        int pt = p + (nt0 + t) * 16;
        ushort4 u;
        u.x = f2bf(fmaxf(acc[t].x, 0.f)); u.y = f2bf(fmaxf(acc[t].y, 0.f));
        u.z = f2bf(fmaxf(acc[t].z, 0.f)); u.w = f2bf(fmaxf(acc[t].w, 0.f));
        *(ushort4*)(Xout + pt * sout + ch0) = u;
    }
}

__device__ __forceinline__ float fold16(const f32x16 a) {
    float t0 = fminf(fminf(a[0], a[1]), a[2]);
    float t1 = fminf(fminf(a[3], a[4]), a[5]);
    float t2 = fminf(fminf(a[6], a[7]), a[8]);
    float t3 = fminf(fminf(a[9], a[10]), a[11]);
    float t4 = fminf(fminf(a[12], a[13]), a[14]);
    float s0 = fminf(fminf(t0, t1), t2);
    float s1 = fminf(fminf(t3, t4), a[15]);
    return fminf(s0, s1);
}

// dist for one point from swizzled tables: 4x ds_read_b64 + 4 MFMA
__device__ __forceinline__ void dist_point_tbl(const ushort_t* __restrict__ SM,
                                               int pt, int lane, float* __restrict__ DMIN) {
    const short8 zero8 = {0, 0, 0, 0, 0, 0, 0, 0};
    const int m32 = lane & 31;
    const int h2  = lane >> 5;
    const int sw  = pt & 7;
    short8 af[2], bfr[2];
    #pragma unroll
    for (int c = 0; c < 2; ++c) {
        int k   = c * 32 + m32;
        int idx = pt * 256 + ((k >> 1) ^ sw) * 8 + (k & 1) * 4;
        ushort4 ra = *(const ushort4*)(SM + S_DA + idx);
        ushort4 rb = *(const ushort4*)(SM + S_DI + idx);
        short8 t = zero8;
        t[0] = (short)ra.x; t[1] = (short)ra.y; t[2] = (short)ra.z;
        t[3] = (short)ra.w; t[4] = (short)0x3F80;
        af[c] = h2 ? zero8 : t;
        short8 s = zero8;
        s[0] = (short)rb.x; s[1] = (short)rb.y; s[2] = (short)rb.z;
        s[3] = (short)0x3F80; s[4] = (short)rb.w;
        bfr[c] = h2 ? zero8 : s;
    }
    float dmin = 3.0e38f;
    #pragma unroll
    for (int kc = 0; kc < 2; ++kc) {
        #pragma unroll
        for (int lc = 0; lc < 2; ++lc) {
            f32x16 acc = {0.f,0.f,0.f,0.f,0.f,0.f,0.f,0.f,
                          0.f,0.f,0.f,0.f,0.f,0.f,0.f,0.f};
            acc = __builtin_amdgcn_mfma_f32_32x32x16_bf16(af[kc], bfr[lc], acc, 0, 0, 0);
            dmin = fminf(dmin, fold16(acc));
        }
    }
    #pragma unroll
    for (int off = 32; off > 0; off >>= 1)
        dmin = fminf(dmin, __shfl_xor(dmin, off, 64));
    if (lane == 0) DMIN[pt] = dmin;
}

__global__ __launch_bounds__(512, 8)
void fused_all(const float* __restrict__ img,   // [4][3][8192][64]
               const float* __restrict__ knn,   // [4][3][64][8192]
               const float* __restrict__ pts,   // [4][3][8192]
               const float* __restrict__ f2d,   // [4][64][8192]
               const float* __restrict__ fw1p, const float* __restrict__ fw2p,
               const float* __restrict__ fw3p,
               const ushort_t* __restrict__ wsp, float* __restrict__ out)
{
    __shared__ ushort_t SMEM[19456];
    __shared__ float DMIN[16];
    __shared__ float RBUF[3][4][16];

    const int tid  = threadIdx.x;
    const int wid  = __builtin_amdgcn_readfirstlane(tid >> 6);
    const int lane = tid & 63;
    const int p16  = lane & 15;
    const int h    = lane >> 4;
    const int b    = blockIdx.x >> 9;
    const int n0   = (blockIdx.x & 511) << 4;

    const int mt64 = wid & 3;
    const int nt1  = wid >> 2;

    const float* fbias = (const float*)wsp + FBF;
    f32x4 a2[2], a1[1];
    float fpre[4] = {0.f, 0.f, 0.f, 0.f};
    f32x4 c3acc = (f32x4){0.f, 0.f, 0.f, 0.f};

    // ======= phase 0: stage knn/img + build centered dist tables ===========
    for (int e = tid; e < 32 * 29; e += 512) {           // X1 zero cols 195..223
        int r = e / 29, c = 195 + e % 29;
        SMEM[S_X1 + r * ST1 + c] = 0;
    }
    {   // knn -> rows 0..15 + DA table; thread = (pt, k-pair)
        int pt = tid & 15, kk = tid >> 4;                // kk 0..31
        int k0 = kk << 1;
        int kx = (kk ^ (pt & 7)) << 1;                   // swizzled pair slot
        float pxv[3], rcn[2][3];
        #pragma unroll
        for (int c = 0; c < 3; ++c)
            pxv[c] = bf2f(f2bf(pts[((size_t)(b * 3 + c)) * N_PTS + n0 + pt]));
        #pragma unroll
        for (int c = 0; c < 3; ++c) {
            const float* base = knn + ((size_t)(b * 3 + c) * 64 + k0) * N_PTS + n0 + pt;
            ushort2 u;
            u.x = f2bf(base[0]);
            u.y = f2bf(base[(size_t)N_PTS]);
            *(ushort2*)(SMEM + S_X1 + pt * ST1 + c * 64 + k0) = u;
            rcn[0][c] = bf2f(u.x) - pxv[c];
            rcn[1][c] = bf2f(u.y) - pxv[c];
        }
        float r20 = fmaf(rcn[0][0], rcn[0][0], fmaf(rcn[0][1], rcn[0][1], rcn[0][2] * rcn[0][2]));
        float r21 = fmaf(rcn[1][0], rcn[1][0], fmaf(rcn[1][1], rcn[1][1], rcn[1][2] * rcn[1][2]));
        ushort4 lo, hi;
        lo.x = f2bf(-2.0f * rcn[0][0]); lo.y = f2bf(-2.0f * rcn[0][1]);
        lo.z = f2bf(-2.0f * rcn[0][2]); lo.w = f2bf(r20);
        hi.x = f2bf(-2.0f * rcn[1][0]); hi.y = f2bf(-2.0f * rcn[1][1]);
        hi.z = f2bf(-2.0f * rcn[1][2]); hi.w = f2bf(r21);
        *(ushort4*)(SMEM + S_DA + (pt * 64 + kx) * 4)     = lo;
        *(ushort4*)(SMEM + S_DA + (pt * 64 + kx) * 4 + 4) = hi;
    }
    {   // img -> rows 16..31 + DI table; thread = (pt, k-pair)
        int pt = tid >> 5, kk = tid & 31;
        int k0 = kk << 1;
        int kx = (kk ^ (pt & 7)) << 1;                   // swizzled pair slot
        float pxv[3], icn[2][3];
        #pragma unroll
        for (int c = 0; c < 3; ++c)
            pxv[c] = bf2f(f2bf(pts[((size_t)(b * 3 + c)) * N_PTS + n0 + pt]));
        #pragma unroll
        for (int c = 0; c < 3; ++c) {
            float2 v = *(const float2*)(img + (((size_t)(b * 3 + c)) * N_PTS + n0 + pt) * 64 + k0);
            ushort2 u;
            u.x = f2bf(v.x); u.y = f2bf(v.y);
            *(ushort2*)(SMEM + S_X1 + (16 + pt) * ST1 + c * 64 + k0) = u;
            icn[0][c] = bf2f(u.x) - pxv[c];
            icn[1][c] = bf2f(u.y) - pxv[c];
        }
        float i20 = fmaf(icn[0][0], icn[0][0], fmaf(icn[0][1], icn[0][1], icn[0][2] * icn[0][2]));
        float i21 = fmaf(icn[1][0], icn[1][0], fmaf(icn[1][1], icn[1][1], icn[1][2] * icn[1][2]));
        ushort4 lo, hi;
        lo.x = f2bf(icn[0][0]); lo.y = f2bf(icn[0][1]);
        lo.z = f2bf(icn[0][2]); lo.w = f2bf(i20);
        hi.x = f2bf(icn[1][0]); hi.y = f2bf(icn[1][1]);
        hi.z = f2bf(icn[1][2]); hi.w = f2bf(i21);
        *(ushort4*)(SMEM + S_DI + (pt * 64 + kx) * 4)     = lo;
        *(ushort4*)(SMEM + S_DI + (pt * 64 + kx) * 4 + 4) = hi;
    }
    if (tid < 96) {                                      // pts ch 192..194, all rows
        int c = tid >> 5, r = tid & 31;
        SMEM[S_X1 + r * ST1 + 192 + c] = f2bf(pts[((size_t)(b * 3 + c)) * N_PTS + n0 + (r & 15)]);
    }
    __syncthreads();   // B1

    // ======= phase 1a: dist from tables (tables die after this) ============
    dist_point_tbl(SMEM, wid * 2, lane, DMIN);
    dist_point_tbl(SMEM, wid * 2 + 1, lane, DMIN);
    __syncthreads();   // B1.5

    // ======= phase 1b: L1 (32 rows) — writes X2 (over DA) ==================
    mfma_tiles<7, 2>((const short8*)(wsp + WP1), fbias + FB_L1, wid, 0,
                     SMEM + S_X1, ST1, lane, a2);
    epi_relu_lds<2>(a2, wid, 0, h, p16, SMEM + S_X2, ST2);
    __syncthreads();   // B2

    // ======= phase 2: L2A (32 rows) — writes X3A (over DI) =================
    mfma_tiles<4, 1>((const short8*)(wsp + WP2A), fbias + FB_2A, mt64, nt1,
                     SMEM + S_X2, ST2, lane, a1);
    epi_relu_lds<1>(a1, mt64, nt1, h, p16, SMEM + S_X3A, ST3);
    __syncthreads();   // B3

    // ======= phase 3: L2B + SHAL stores ====================================
    mfma_tiles<2, 1>((const short8*)(wsp + WP2B), fbias + FB_2B, mt64, nt1,
                     SMEM + S_X3A, ST3, lane, a1);
    {
        int ch0 = mt64 * 16 + h * 4;
        int row = p16 + nt1 * 16;
        float v0 = fmaxf(a1[0].x, 0.f), v1 = fmaxf(a1[0].y, 0.f);
        float v2 = fmaxf(a1[0].z, 0.f), v3 = fmaxf(a1[0].w, 0.f);
        ushort4 u;
        u.x = f2bf(v0); u.y = f2bf(v1); u.z = f2bf(v2); u.w = f2bf(v3);
        *(ushort4*)(SMEM + S_X3B + row * ST3 + ch0) = u;
        if (nt1 == 0) {
            size_t base = OUT_SHAL + ((size_t)(b * 64 + ch0)) * N_PTS + n0 + p16;
            out[base]             = v0;
            out[base + N_PTS]     = v1;
            out[base + 2 * N_PTS] = v2;
            out[base + 3 * N_PTS] = v3;
        }
    }
    __syncthreads();   // B4

    // ======= phase 4: LIN+cos (waves 0..3) | statics+preload (4..7) ========
    if (wid < 4) {
        f32x4 sv[2];
        mfma_tiles<2, 2>((const short8*)(wsp + WLIN), fbias + FB_LIN, wid, 0,
                         SMEM + S_X3B, ST3, lane, sv);
        float pn = sv[0].x * sv[1].x + sv[0].y * sv[1].y + sv[0].z * sv[1].z + sv[0].w * sv[1].w;
        float pr = sv[0].x * sv[0].x + sv[0].y * sv[0].y + sv[0].z * sv[0].z + sv[0].w * sv[0].w;
        float pi = sv[1].x * sv[1].x + sv[1].y * sv[1].y + sv[1].z * sv[1].z + sv[1].w * sv[1].w;
        pn += __shfl_xor(pn, 16, 64); pn += __shfl_xor(pn, 32, 64);
        pr += __shfl_xor(pr, 16, 64); pr += __shfl_xor(pr, 32, 64);
        pi += __shfl_xor(pi, 16, 64); pi += __shfl_xor(pi, 32, 64);
        if (lane < 16) {
            RBUF[0][wid][p16] = pn;
            RBUF[1][wid][p16] = pr;
            RBUF[2][wid][p16] = pi;
        }
    } else {
        int t256 = tid - 256;                            // 0..255
        int pt = t256 & 15, cg = t256 >> 4;
        #pragma unroll
        for (int r = 0; r < 4; ++r)
            fpre[r] = f2d[((size_t)(b * 64 + cg * 4 + r)) * N_PTS + n0 + pt];
        if (t256 < 48) {                                 // X4 pts ch64..66
            int c = t256 >> 4, r = t256 & 15;
            SMEM[S_X4 + r * ST3 + 64 + c] = f2bf(pts[((size_t)(b * 3 + c)) * N_PTS + n0 + r]);
        }
        for (int e = t256; e < 16 * 29; e += 256) {      // X4 zero cols 67..95
            int r = e / 29, c = 67 + e % 29;
            SMEM[S_X4 + r * ST3 + c] = 0;
        }
    }
    __syncthreads();   // B5

    // ======= phase 5: sim+F2 (waves 4..7) | C3A part1 over X3B (0..3) ======
    if (wid >= 4) {
        int t256 = tid - 256;
        int pt = t256 & 15, cg = t256 >> 4;
        float num = 0.f, rr = 0.f, ii = 0.f;
        #pragma unroll
        for (int m = 0; m < 4; ++m) {
            num += RBUF[0][m][pt];
            rr  += RBUF[1][m][pt];
            ii  += RBUF[2][m][pt];
        }
        float den = fmaxf(sqrtf(rr) * sqrtf(ii), 1e-8f);
        float geo = expf(-(1.0f / fw1p[0]) * DMIN[pt]) + fw2p[0];
        float sim = (num / den) * geo;
        ushort4 u;
        u.x = f2bf(sim * fpre[0]); u.y = f2bf(sim * fpre[1]);
        u.z = f2bf(sim * fpre[2]); u.w = f2bf(sim * fpre[3]);
        *(ushort4*)(SMEM + S_F2 + pt * ST3 + cg * 4) = u;
        if (cg == 0) {
            out[OUT_SIM  + (size_t)b * N_PTS + n0 + pt] = sim;
            out[OUT_DSIM + (size_t)b * N_PTS + n0 + pt] = fw3p[0];
        }
    } else {
        // C3A ks 0..1 (X3B half) — accumulator carried across B6
        const short8* W = (const short8*)(wsp + WC3A);
        float4 b4 = *(const float4*)(fbias + FB_3A + wid * 16 + (h << 2));
        c3acc = (f32x4){b4.x, b4.y, b4.z, b4.w};
        int row = p16 * ST3 + (h << 3);
        #pragma unroll
        for (int ks = 0; ks < 2; ++ks) {
            short8 aw = W[(wid * 4 + ks) * 64 + lane];
            const ushort_t* src = SMEM + S_X3B + row + ks * 32;
            c3acc = __builtin_amdgcn_mfma_f32_16x16x32_bf16(aw, *(const short8*)src, c3acc, 0, 0, 0);
        }
    }
    __syncthreads();   // B6

    // ======= phase 6: C3A part2 (F2 half) -> X3A rows 0..15 ================
    if (wid < 4) {
        const short8* W = (const short8*)(wsp + WC3A);
        int row = p16 * ST3 + (h << 3);
        #pragma unroll
        for (int ks = 2; ks < 4; ++ks) {
            short8 aw = W[(wid * 4 + ks) * 64 + lane];
            const ushort_t* src = SMEM + S_F2 + row + (ks - 2) * 32;
            c3acc = __builtin_amdgcn_mfma_f32_16x16x32_bf16(aw, *(const short8*)src, c3acc, 0, 0, 0);
        }
        a1[0] = c3acc;
        epi_relu_lds<1>(a1, wid, 0, h, p16, SMEM + S_X3A, ST3);
    }
    __syncthreads();   // B7

    // ======= phase 7: C3B -> X4 ch0..63 rows 0..15 =========================
    if (wid < 4) {
        mfma_tiles<2, 1>((const short8*)(wsp + WC3B), fbias + FB_3B, wid, 0,
                         SMEM + S_X3A, ST3, lane, a1);
        epi_relu_lds<1>(a1, wid, 0, h, p16, SMEM + S_X4, ST3);
    }
    __syncthreads();   // B8

    // ======= phase 8: PN2 -> deeprealfeat ==================================
    mfma_tiles<3, 1>((const short8*)(wsp + WPN), fbias + FB_PN, wid, 0,
                     SMEM + S_X4, ST3, lane, a1);
    {
        int ch0 = wid * 16 + h * 4;
        size_t base = OUT_DEEP + ((size_t)(b * 128 + ch0)) * N_PTS + n0 + p16;
        out[base]             = fmaxf(a1[0].x, 0.f);
        out[base + N_PTS]     = fmaxf(a1[0].y, 0.f);
        out[base + 2 * N_PTS] = fmaxf(a1[0].z, 0.f);
        out[base + 3 * N_PTS] = fmaxf(a1[0].w, 0.f);
    }
}

extern "C" void kernel_launch(void* const* d_in, const int* in_sizes, int n_in,
                              void* d_out, int out_size, void* d_ws, size_t ws_size,
                              hipStream_t stream) {
    const float* img    = (const float*)d_in[0];
    const float* knn    = (const float*)d_in[1];
    const float* pts    = (const float*)d_in[2];
    const float* f2d    = (const float*)d_in[3];
    const float* sift_W = (const float*)d_in[4];
    const float* sift_b = (const float*)d_in[5];
    const float* sift_g = (const float*)d_in[6];
    const float* sift_bt= (const float*)d_in[7];
    const float* c2_W1  = (const float*)d_in[8];
    const float* c2_b1  = (const float*)d_in[9];
    const float* c2_g1  = (const float*)d_in[10];
    const float* c2_bt1 = (const float*)d_in[11];
    const float* c2_W2  = (const float*)d_in[12];
    const float* c2_b2  = (const float*)d_in[13];
    const float* c2_g2  = (const float*)d_in[14];
    const float* c2_bt2 = (const float*)d_in[15];
    const float* lin1_W = (const float*)d_in[16];
    const float* lin1_b = (const float*)d_in[17];
    const float* c3_W1  = (const float*)d_in[18];
    const float* c3_b1  = (const float*)d_in[19];
    const float* c3_g1  = (const float*)d_in[20];
    const float* c3_bt1 = (const float*)d_in[21];
    const float* c3_W2  = (const float*)d_in[22];
    const float* c3_b2  = (const float*)d_in[23];
    const float* c3_g2  = (const float*)d_in[24];
    const float* c3_bt2 = (const float*)d_in[25];
    const float* pn2_W  = (const float*)d_in[26];
    const float* pn2_b  = (const float*)d_in[27];
    const float* pn2_g  = (const float*)d_in[28];
    const float* pn2_bt = (const float*)d_in[29];
    const float* fw1    = (const float*)d_in[30];
    const float* fw2    = (const float*)d_in[31];
    const float* fw3    = (const float*)d_in[32];

    ushort_t* wsp = (ushort_t*)d_ws;
    float* out = (float*)d_out;

    prep_all<<<37, 256, 0, stream>>>(
        sift_W, sift_b, sift_g, sift_bt,
        c2_W1, c2_b1, c2_g1, c2_bt1,
        c2_W2, c2_b2, c2_g2, c2_bt2,
        lin1_W, lin1_b,
        c3_W1, c3_b1, c3_g1, c3_bt1,
        c3_W2, c3_b2, c3_g2, c3_bt2,
        pn2_W, pn2_b, pn2_g, pn2_bt,
        wsp);

    fused_all<<<2048, 512, 0, stream>>>(img, knn, pts, f2d, fw1, fw2, fw3, wsp, out);
}